// Round 5
// baseline (681.532 us; speedup 1.0000x reference)
//
#include <hip/hip_runtime.h>
#include <hip/hip_bf16.h>

#define S_ 1024
#define P_ 1024
#define B_ 4
#define E_ 1024
#define J_ 2048
#define H_ 16
#define I_ 64

typedef __bf16 bf16_t;
typedef __bf16 bf16x8 __attribute__((ext_vector_type(8)));
typedef __bf16 bf16x4 __attribute__((ext_vector_type(4)));
typedef unsigned short u16x8 __attribute__((ext_vector_type(8)));
typedef float f32x4 __attribute__((ext_vector_type(4)));

#define MFMA16(a, b, c) __builtin_amdgcn_mfma_f32_16x16x32_bf16(a, b, c, 0, 0, 0)

// XOR-granule swizzle for stride-64 bf16 LDS tiles (flash only).
#define SWZ(r, c) (((r) << 6) + ((((((c) >> 3)) ^ ((r) & 7)) << 3)) + ((c) & 7))

// ---------------- fused fp32 -> bf16 converts (memory, inputMHA, posEmb) ----------------
__global__ __launch_bounds__(256) void cvt_all_kernel(const float* __restrict__ memory,
                                                      const float* __restrict__ input,
                                                      const float* __restrict__ posEmb,
                                                      bf16_t* __restrict__ Xbf,
                                                      bf16_t* __restrict__ Pemb) {
    int blk = blockIdx.x;
    const float* src;
    bf16_t* dst;
    if (blk < 4096) { src = memory; dst = Xbf; }
    else if (blk < 8192) { blk -= 4096; src = input; dst = Xbf + (size_t)P_ * B_ * E_; }
    else { blk -= 8192; src = posEmb; dst = Pemb; }
    int i = (blk * 256 + threadIdx.x) * 4;
    float4 v = *(const float4*)(src + i);
    bf16x4 o = {(bf16_t)v.x, (bf16_t)v.y, (bf16_t)v.z, (bf16_t)v.w};
    *(bf16x4*)(dst + i) = o;
}

// ---------------- fused weight transposes: W (K x N) fp32 -> W^T (N x K) bf16 ----------------
__global__ void trans_all_kernel(const float* __restrict__ W_kv, bf16_t* __restrict__ Wkvt,
                                 const float* __restrict__ W_q, bf16_t* __restrict__ Wqt,
                                 const float* __restrict__ W_p, bf16_t* __restrict__ Wpt,
                                 const float* __restrict__ W_o, bf16_t* __restrict__ Wot) {
    __shared__ float tile[32][33];
    int z = blockIdx.z;
    const float* W = (z == 0) ? W_kv : (z == 1) ? W_q : (z == 2) ? W_p : W_o;
    bf16_t* Wt = (z == 0) ? Wkvt : (z == 1) ? Wqt : (z == 2) ? Wpt : Wot;
    int N = (z == 0) ? 2048 : 1024;
    if (blockIdx.x * 32 >= N) return;
    int n0 = blockIdx.x * 32, k0 = blockIdx.y * 32;
    int x = threadIdx.x, y = threadIdx.y;
    for (int i = 0; i < 32; i += 8)
        tile[y + i][x] = W[(size_t)(k0 + y + i) * N + n0 + x];
    __syncthreads();
    for (int i = 0; i < 32; i += 8)
        Wt[(size_t)(n0 + y + i) * 1024 + k0 + x] = (bf16_t)tile[x][y + i];  // K == 1024 always
}

// ---------------- bf16 MFMA GEMM tile body ----------------
__device__ __forceinline__ void gemm_tile(
    const bf16_t* __restrict__ A, const bf16_t* __restrict__ Bt, int N,
    int m0, int n0, int epi,
    bf16_t* __restrict__ out0, bf16_t* __restrict__ out1,
    const float* __restrict__ add0, const float* __restrict__ add1,
    float* __restrict__ outf,
    bf16_t (*Al)[72], bf16_t (*Bl)[72]) {
    const int K = 1024;
    int tid = threadIdx.x;
    int wave = tid >> 6, lane = tid & 63, quad = lane >> 4, l16 = lane & 15;
    int wm = (wave & 1) * 64, wn = (wave >> 1) * 64;
    f32x4 zero = {0.f, 0.f, 0.f, 0.f};
    f32x4 acc[4][4];
    #pragma unroll
    for (int i = 0; i < 4; i++)
        #pragma unroll
        for (int j = 0; j < 4; j++) acc[i][j] = zero;

    for (int k0 = 0; k0 < K; k0 += 64) {
        __syncthreads();
        #pragma unroll
        for (int r = 0; r < 4; r++) {
            int idx = tid + 256 * r;
            int row = idx >> 3, seg = (idx & 7) * 8;
            *(uint4*)&Al[row][seg] = *(const uint4*)&A[(size_t)(m0 + row) * K + k0 + seg];
            *(uint4*)&Bl[row][seg] = *(const uint4*)&Bt[(size_t)(n0 + row) * K + k0 + seg];
        }
        __syncthreads();
        #pragma unroll
        for (int ks = 0; ks < 2; ks++) {
            bf16x8 af[4], bfr[4];
            #pragma unroll
            for (int i = 0; i < 4; i++)
                af[i] = *(const bf16x8*)&Al[wm + i * 16 + l16][ks * 32 + quad * 8];
            #pragma unroll
            for (int j = 0; j < 4; j++)
                bfr[j] = *(const bf16x8*)&Bl[wn + j * 16 + l16][ks * 32 + quad * 8];
            #pragma unroll
            for (int i = 0; i < 4; i++)
                #pragma unroll
                for (int j = 0; j < 4; j++) acc[i][j] = MFMA16(af[i], bfr[j], acc[i][j]);
        }
    }
    #pragma unroll
    for (int i = 0; i < 4; i++)
        #pragma unroll
        for (int j = 0; j < 4; j++)
            #pragma unroll
            for (int reg = 0; reg < 4; reg++) {
                int m = m0 + wm + i * 16 + quad * 4 + reg;
                int n = n0 + wn + j * 16 + l16;
                float v = acc[i][j][reg];
                if (epi == 0) {
                    out0[(size_t)m * N + n] = (bf16_t)v;
                } else if (epi == 1) {
                    out0[(size_t)m * N + n] = (bf16_t)(v + add0[n]);
                    out1[(size_t)m * N + n] = (bf16_t)(v + add1[n]);
                } else {
                    outf[(size_t)m * N + n] = v + add0[(size_t)m * N + n];
                }
            }
}

// ---------------- packed pre-attention GEMMs: kv | q(+u,+v dual) | p ----------------
__global__ __launch_bounds__(256) void gemm3_kernel(
    const bf16_t* __restrict__ Xbf, const bf16_t* __restrict__ Wkvt, bf16_t* __restrict__ kvb,
    const bf16_t* __restrict__ Wqt, bf16_t* __restrict__ qub, bf16_t* __restrict__ qvb,
    const float* __restrict__ u, const float* __restrict__ v,
    const bf16_t* __restrict__ Pemb, const bf16_t* __restrict__ Wpt, bf16_t* __restrict__ pb) {
    __shared__ __attribute__((aligned(16))) bf16_t Al[128][72];
    __shared__ __attribute__((aligned(16))) bf16_t Bl[128][72];
    int id = blockIdx.x;
    if (id < 1024) {
        gemm_tile(Xbf, Wkvt, 2048, (id >> 4) * 128, (id & 15) * 128, 0,
                  kvb, nullptr, nullptr, nullptr, nullptr, Al, Bl);
    } else if (id < 1280) {
        int t = id - 1024;
        gemm_tile(Xbf + (size_t)P_ * B_ * E_, Wqt, 1024, (t >> 3) * 128, (t & 7) * 128, 1,
                  qub, qvb, u, v, nullptr, Al, Bl);
    } else {
        int t = id - 1280;
        gemm_tile(Pemb, Wpt, 1024, (t >> 3) * 128, (t & 7) * 128, 0,
                  pb, nullptr, nullptr, nullptr, nullptr, Al, Bl);
    }
}

// ---------------- output GEMM: opre = awv @ W_o + inputMHA (fp32) ----------------
__global__ __launch_bounds__(256) void gemmo_kernel(
    const bf16_t* __restrict__ awvb, const bf16_t* __restrict__ Wot,
    const float* __restrict__ inputMHA, float* __restrict__ opre) {
    __shared__ __attribute__((aligned(16))) bf16_t Al[128][72];
    __shared__ __attribute__((aligned(16))) bf16_t Bl[128][72];
    int id = blockIdx.x;
    gemm_tile(awvb, Wot, 1024, (id >> 3) * 128, (id & 7) * 128, 2,
              nullptr, nullptr, inputMHA, nullptr, opre, Al, Bl);
}

// ---------------- fused flash attention (R5: 1-deep pipelined ep) ----------------
// Content+PV path = proven flash_pos structure (24KB LDS, ready pos fragment pq
// consumed by exp2). Position path computed IN-KERNEL but pipelined one iteration
// deep, registers only: p-loads(it+1) issued at it-top; ep-MFMA+shuffles(it+1) run
// in the barrier zone at it-end; exp2(it) always consumes a READY pq. No pos
// intermediate in DRAM, no Plds ring, no dependent-load stall in the exp2 chain.
__global__ __launch_bounds__(256) void flash_fused_kernel(
    const bf16_t* __restrict__ qu, const bf16_t* __restrict__ qv,
    const bf16_t* __restrict__ kv, const bf16_t* __restrict__ pb,
    float* __restrict__ Oacc, float* __restrict__ lacc) {
    __shared__ __attribute__((aligned(16))) bf16_t Klds[64 * 64];
    __shared__ __attribute__((aligned(16))) bf16_t Vt[64 * 64];
    __shared__ __attribute__((aligned(16))) bf16_t Prob[4 * 16 * 64];

    int tid = threadIdx.x;
    int wave = tid >> 6, lane = tid & 63, quad = lane >> 4, l16 = lane & 15;

    int x = blockIdx.x;
    int s_blk, c;
    if (x < 24) { s_blk = x / 3; c = x - s_blk * 3; }
    else        { int y = x - 24; s_blk = 8 + (y >> 2); c = y & 3; }
    int nt = 17 + s_blk;
    int t0 = c * 8;
    int t1 = t0 + 8; if (t1 > nt) t1 = nt;

    int s0 = s_blk * 64;
    int bh = blockIdx.y;
    int b = bh >> 4, h = bh & 15;
    int srow0 = s0 + wave * 16;

    const bf16_t* qub = qu + ((size_t)(srow0 + l16) * B_ + b) * 1024 + h * 64 + quad * 8;
    const bf16_t* qvb = qv + ((size_t)(srow0 + l16) * B_ + b) * 1024 + h * 64 + quad * 8;
    bf16x8 aqu0 = *(const bf16x8*)(qub);
    bf16x8 aqu1 = *(const bf16x8*)(qub + 32);
    bf16x8 aqv0 = *(const bf16x8*)(qvb);
    bf16x8 aqv1 = *(const bf16x8*)(qvb + 32);

    f32x4 zero = {0.f, 0.f, 0.f, 0.f};
    f32x4 accO[4];
    #pragma unroll
    for (int ot = 0; ot < 4; ot++) accO[ot] = zero;
    float lrowp[4] = {0.f, 0.f, 0.f, 0.f};

    const int dbase = 1008 - srow0;  // p-row of ep tile t at chunk j0: d = j0+dbase+t*16+l16
    const float SCL = 0.125f * 1.44269504088896f;

    int jr = tid >> 3, seg8g = tid & 7;
    int jp = tid & 31, iseg = tid >> 5;
    uint* VtU = (uint*)&Vt[0];
    bf16_t* ProbW = Prob + (wave << 10);
    const bf16_t* pbh = pb + h * 64 + quad * 8;

    // shuffle realign constants (per thread, loop-invariant)
    // out row r=quad*4+reg, col l16: idx=l16+15-r; srcl=quad*16+(idx&15); sel idx<16
    bf16x4 pq[4];   // READY pos fragment for current iteration

    {
        int j0 = t0 * 64;
        // p rows for FIRST iteration
        bf16x8 bp0[5], bp1[5];
        #pragma unroll
        for (int t = 0; t < 5; t++) {
            int d = j0 + dbase + t * 16 + l16;
            if (d > J_ - 1) d = J_ - 1;
            const bf16_t* pp = pbh + (size_t)d * 1024;
            bp0[t] = *(const bf16x8*)pp;
            bp1[t] = *(const bf16x8*)(pp + 32);
        }
        // K/V initial stage
        const bf16_t* kp = kv + ((size_t)(j0 + jr) * B_ + b) * 2048 + h * 64 + seg8g * 8;
        uint4 ka = *(const uint4*)kp;
        uint4 kb = *(const uint4*)(kp + (size_t)32 * B_ * 2048);
        const bf16_t* vp = kv + ((size_t)(j0 + jp * 2) * B_ + b) * 2048 + 1024 + h * 64 + iseg * 8;
        u16x8 va = *(const u16x8*)vp;
        u16x8 vb = *(const u16x8*)(vp + (size_t)B_ * 2048);
        *(uint4*)&Klds[SWZ(jr, seg8g * 8)] = ka;
        *(uint4*)&Klds[SWZ(jr + 32, seg8g * 8)] = kb;
        #pragma unroll
        for (int e = 0; e < 8; e++) {
            int row = iseg * 8 + e;
            VtU[(row << 5) + ((((jp >> 2) ^ (row & 7)) << 2)) + (jp & 3)] =
                (uint)va[e] | ((uint)vb[e] << 16);
        }
        // ep(t0) + realign -> pq (register-only, overlaps barrier wait)
        f32x4 ep[5];
        #pragma unroll
        for (int t = 0; t < 5; t++)
            ep[t] = MFMA16(aqv1, bp1[t], MFMA16(aqv0, bp0[t], zero));
        #pragma unroll
        for (int reg = 0; reg < 4; reg++) {
            int r = quad * 4 + reg;
            int idx = l16 + 15 - r;
            int srcl = quad * 16 + (idx & 15);
            float sh[5];
            #pragma unroll
            for (int t = 0; t < 5; t++) sh[t] = __shfl(ep[t][reg], srcl);
            #pragma unroll
            for (int t = 0; t < 4; t++) pq[t][reg] = (bf16_t)((idx < 16) ? sh[t] : sh[t + 1]);
        }
    }
    __syncthreads();

    for (int it = t0; it < t1; it++) {
        int j0 = it * 64;
        bool pf = (it + 1 < t1);

        // issue NEXT iteration's p loads first (oldest in vmcnt queue; a full
        // iteration of compute covers their latency)
        bf16x8 bpn0[5], bpn1[5];
        uint4 ka, kb;
        u16x8 va, vb;
        if (pf) {
            int j1 = j0 + 64;
            #pragma unroll
            for (int t = 0; t < 5; t++) {
                int d = j1 + dbase + t * 16 + l16;
                if (d > J_ - 1) d = J_ - 1;
                const bf16_t* pp = pbh + (size_t)d * 1024;
                bpn0[t] = *(const bf16x8*)pp;
                bpn1[t] = *(const bf16x8*)(pp + 32);
            }
            const bf16_t* kp = kv + ((size_t)(j1 + jr) * B_ + b) * 2048 + h * 64 + seg8g * 8;
            ka = *(const uint4*)kp;
            kb = *(const uint4*)(kp + (size_t)32 * B_ * 2048);
            const bf16_t* vp = kv + ((size_t)(j1 + jp * 2) * B_ + b) * 2048 + 1024 + h * 64 + iseg * 8;
            va = *(const u16x8*)vp;
            vb = *(const u16x8*)(vp + (size_t)B_ * 2048);
        }

        // content scores from K in LDS
        f32x4 cs[4];
        #pragma unroll
        for (int t = 0; t < 4; t++) cs[t] = zero;
        __builtin_amdgcn_s_setprio(1);
        #pragma unroll
        for (int ks = 0; ks < 2; ks++) {
            bf16x8 aq = ks ? aqu1 : aqu0;
            #pragma unroll
            for (int t = 0; t < 4; t++) {
                bf16x8 bk = *(const bf16x8*)&Klds[SWZ(t * 16 + l16, ks * 32 + quad * 8)];
                cs[t] = MFMA16(aq, bk, cs[t]);
            }
        }
        __builtin_amdgcn_s_setprio(0);

        // softmax numerators: pos fragment pq is READY (computed last iteration)
        #pragma unroll
        for (int reg = 0; reg < 4; reg++) {
            int r = quad * 4 + reg;
            int s = srow0 + r;
            float psum = 0.f;
            #pragma unroll
            for (int t = 0; t < 4; t++) {
                float p = exp2f((cs[t][reg] + (float)pq[t][reg]) * SCL);
                p = (j0 + t * 16 + l16 > P_ + s) ? 0.f : p;  // mask kills clamped-d garbage
                ProbW[SWZ(r, t * 16 + l16)] = (bf16_t)p;
                psum += p;
            }
            lrowp[reg] += psum;
        }

        __builtin_amdgcn_s_setprio(1);
        #pragma unroll
        for (int ks = 0; ks < 2; ks++) {
            bf16x8 pa = *(const bf16x8*)&Prob[(wave << 10) + SWZ(l16, ks * 32 + quad * 8)];
            #pragma unroll
            for (int ot = 0; ot < 4; ot++) {
                bf16x8 bv = *(const bf16x8*)&Vt[SWZ(ot * 16 + l16, ks * 32 + quad * 8)];
                accO[ot] = MFMA16(pa, bv, accO[ot]);
            }
        }
        __builtin_amdgcn_s_setprio(0);

        __syncthreads();
        if (pf) {
            // K/V stage for it+1
            *(uint4*)&Klds[SWZ(jr, seg8g * 8)] = ka;
            *(uint4*)&Klds[SWZ(jr + 32, seg8g * 8)] = kb;
            #pragma unroll
            for (int e2 = 0; e2 < 8; e2++) {
                int row = iseg * 8 + e2;
                VtU[(row << 5) + ((((jp >> 2) ^ (row & 7)) << 2)) + (jp & 3)] =
                    (uint)va[e2] | ((uint)vb[e2] << 16);
            }
            // ep(it+1) + realign -> pq (register-only; overlaps barrier wait)
            f32x4 ep[5];
            #pragma unroll
            for (int t = 0; t < 5; t++)
                ep[t] = MFMA16(aqv1, bpn1[t], MFMA16(aqv0, bpn0[t], zero));
            #pragma unroll
            for (int reg = 0; reg < 4; reg++) {
                int r = quad * 4 + reg;
                int idx = l16 + 15 - r;
                int srcl = quad * 16 + (idx & 15);
                float sh[5];
                #pragma unroll
                for (int t = 0; t < 5; t++) sh[t] = __shfl(ep[t][reg], srcl);
                #pragma unroll
                for (int t = 0; t < 4; t++) pq[t][reg] = (bf16_t)((idx < 16) ? sh[t] : sh[t + 1]);
            }
        }
        __syncthreads();
    }

    #pragma unroll
    for (int reg = 0; reg < 4; reg++) {
        int r = quad * 4 + reg;
        int srow = srow0 + r;
        float l = lrowp[reg];
        #pragma unroll
        for (int d = 1; d < 16; d <<= 1) l += __shfl_xor(l, d);
        if (l16 == 0) atomicAdd(&lacc[((size_t)srow * B_ + b) * H_ + h], l);
        size_t rowoff = ((size_t)srow * B_ + b) * 1024 + h * 64;
        #pragma unroll
        for (int ot = 0; ot < 4; ot++)
            atomicAdd(&Oacc[rowoff + ot * 16 + l16], accO[ot][reg]);
    }
}

// ---------------- combine/normalize: awv = Oacc / lacc ----------------
__global__ __launch_bounds__(256) void norm_kernel(const float* __restrict__ Oacc,
                                                   const float* __restrict__ lacc,
                                                   bf16_t* __restrict__ awv) {
    int i4 = (blockIdx.x * 256 + threadIdx.x) * 4;
    int row = i4 >> 6;
    float inv = 1.0f / lacc[row];
    float4 o = *(const float4*)(Oacc + i4);
    bf16x4 r = {(bf16_t)(o.x * inv), (bf16_t)(o.y * inv),
                (bf16_t)(o.z * inv), (bf16_t)(o.w * inv)};
    *(bf16x4*)(awv + i4) = r;
}

// ---------------- LayerNorm over E=1024 ----------------
__global__ __launch_bounds__(256) void ln_kernel(const float* __restrict__ x,
                                                 const float* __restrict__ gamma,
                                                 const float* __restrict__ beta,
                                                 float* __restrict__ out) {
    int row = blockIdx.x, tid = threadIdx.x;
    int lane = tid & 63, wave = tid >> 6;
    float4 v = ((const float4*)(x + (size_t)row * 1024))[tid];
    float s = v.x + v.y + v.z + v.w;
    float ss = v.x * v.x + v.y * v.y + v.z * v.z + v.w * v.w;
    #pragma unroll
    for (int sh = 1; sh < 64; sh <<= 1) { s += __shfl_xor(s, sh); ss += __shfl_xor(ss, sh); }
    __shared__ float red[8];
    if (lane == 0) { red[wave] = s; red[4 + wave] = ss; }
    __syncthreads();
    s = red[0] + red[1] + red[2] + red[3];
    ss = red[4] + red[5] + red[6] + red[7];
    float mean = s * (1.f / 1024.f);
    float var = ss * (1.f / 1024.f) - mean * mean;
    float inv = rsqrtf(var + 1e-5f);
    float4 g = ((const float4*)gamma)[tid];
    float4 bt = ((const float4*)beta)[tid];
    float4 o;
    o.x = (v.x - mean) * inv * g.x + bt.x;
    o.y = (v.y - mean) * inv * g.y + bt.y;
    o.z = (v.z - mean) * inv * g.z + bt.z;
    o.w = (v.w - mean) * inv * g.w + bt.w;
    ((float4*)(out + (size_t)row * 1024))[tid] = o;
}

extern "C" void kernel_launch(void* const* d_in, const int* in_sizes, int n_in,
                              void* d_out, int out_size, void* d_ws, size_t ws_size,
                              hipStream_t stream) {
    const float* inputMHA = (const float*)d_in[0];
    const float* posEmb   = (const float*)d_in[1];
    const float* memory   = (const float*)d_in[2];
    const float* u        = (const float*)d_in[3];
    const float* v        = (const float*)d_in[4];
    const float* W_kv     = (const float*)d_in[6];
    const float* W_q      = (const float*)d_in[7];
    const float* W_p      = (const float*)d_in[8];
    const float* W_o      = (const float*)d_in[9];
    const float* gamma    = (const float*)d_in[10];
    const float* beta     = (const float*)d_in[11];
    float* out = (float*)d_out;

    char* ws = (char*)d_ws;
    size_t off = 0;
    auto alloc = [&](size_t bytes) -> void* {
        void* p = ws + off;
        off += (bytes + 255) & ~(size_t)255;
        return p;
    };
    bf16_t* Xbf  = (bf16_t*)alloc((size_t)J_ * B_ * E_ * 2);
    bf16_t* Wkvt = (bf16_t*)alloc((size_t)2048 * 1024 * 2);
    bf16_t* Wqt  = (bf16_t*)alloc((size_t)1024 * 1024 * 2);
    bf16_t* Wpt  = (bf16_t*)alloc((size_t)1024 * 1024 * 2);
    bf16_t* Wot  = (bf16_t*)alloc((size_t)1024 * 1024 * 2);
    bf16_t* Pemb = (bf16_t*)alloc((size_t)2048 * 1024 * 2);
    bf16_t* kvb  = (bf16_t*)alloc((size_t)8192 * 2048 * 2);
    bf16_t* qub  = (bf16_t*)alloc((size_t)4096 * 1024 * 2);
    bf16_t* qvb  = (bf16_t*)alloc((size_t)4096 * 1024 * 2);
    bf16_t* pb   = (bf16_t*)alloc((size_t)2048 * 1024 * 2);
    bf16_t* awvb = (bf16_t*)alloc((size_t)4096 * 1024 * 2);
    float*  opre = (float*)alloc((size_t)4096 * 1024 * 4);
    float*  Oacc = (float*)alloc((size_t)4096 * 1024 * 4);
    float*  lacc = (float*)alloc((size_t)S_ * B_ * H_ * 4);

    hipMemsetAsync(Oacc, 0, (size_t)4096 * 1024 * 4, stream);
    hipMemsetAsync(lacc, 0, (size_t)S_ * B_ * H_ * 4, stream);

    cvt_all_kernel<<<10240, 256, 0, stream>>>(memory, inputMHA, posEmb, Xbf, Pemb);
    trans_all_kernel<<<dim3(64, 32, 4), dim3(32, 8), 0, stream>>>(
        W_kv, Wkvt, W_q, Wqt, W_p, Wpt, W_o, Wot);

    gemm3_kernel<<<1408, 256, 0, stream>>>(Xbf, Wkvt, kvb, Wqt, qub, qvb, u, v, Pemb, Wpt, pb);

    flash_fused_kernel<<<dim3(56, B_ * H_), 256, 0, stream>>>(qub, qvb, kvb, pb, Oacc, lacc);
    norm_kernel<<<4096, 256, 0, stream>>>(Oacc, lacc, awvb);

    gemmo_kernel<<<256, 256, 0, stream>>>(awvb, Wot, inputMHA, opre);
    ln_kernel<<<S_ * B_, 256, 0, stream>>>(opre, gamma, beta, out);
}

// Round 6
// 434.751 us; speedup vs baseline: 1.5676x; 1.5676x over previous
//
#include <hip/hip_runtime.h>
#include <hip/hip_bf16.h>

#define S_ 1024
#define P_ 1024
#define B_ 4
#define E_ 1024
#define J_ 2048
#define H_ 16
#define I_ 64

typedef __bf16 bf16_t;
typedef __bf16 bf16x8 __attribute__((ext_vector_type(8)));
typedef __bf16 bf16x4 __attribute__((ext_vector_type(4)));
typedef unsigned short u16x8 __attribute__((ext_vector_type(8)));
typedef float f32x4 __attribute__((ext_vector_type(4)));

#define MFMA16(a, b, c) __builtin_amdgcn_mfma_f32_16x16x32_bf16(a, b, c, 0, 0, 0)

// XOR-granule swizzle for stride-64 bf16 LDS tiles (flash only).
#define SWZ(r, c) (((r) << 6) + ((((((c) >> 3)) ^ ((r) & 7)) << 3)) + ((c) & 7))

// ---------------- fused fp32 -> bf16 converts (memory, inputMHA, posEmb) ----------------
__global__ __launch_bounds__(256) void cvt_all_kernel(const float* __restrict__ memory,
                                                      const float* __restrict__ input,
                                                      const float* __restrict__ posEmb,
                                                      bf16_t* __restrict__ Xbf,
                                                      bf16_t* __restrict__ Pemb) {
    // segments: [0,4096) memory->Xbf, [4096,8192) input->Xbf+P*B*E, [8192,10240) posEmb->Pemb
    int blk = blockIdx.x;
    const float* src;
    bf16_t* dst;
    if (blk < 4096) { src = memory; dst = Xbf; }
    else if (blk < 8192) { blk -= 4096; src = input; dst = Xbf + (size_t)P_ * B_ * E_; }
    else { blk -= 8192; src = posEmb; dst = Pemb; }
    int i = (blk * 256 + threadIdx.x) * 4;
    float4 v = *(const float4*)(src + i);
    bf16x4 o = {(bf16_t)v.x, (bf16_t)v.y, (bf16_t)v.z, (bf16_t)v.w};
    *(bf16x4*)(dst + i) = o;
}

// ---------------- fused weight transposes: W (K x N) fp32 -> W^T (N x K) bf16 ----------------
__global__ void trans_all_kernel(const float* __restrict__ W_kv, bf16_t* __restrict__ Wkvt,
                                 const float* __restrict__ W_q, bf16_t* __restrict__ Wqt,
                                 const float* __restrict__ W_p, bf16_t* __restrict__ Wpt,
                                 const float* __restrict__ W_o, bf16_t* __restrict__ Wot) {
    __shared__ float tile[32][33];
    int z = blockIdx.z;
    const float* W = (z == 0) ? W_kv : (z == 1) ? W_q : (z == 2) ? W_p : W_o;
    bf16_t* Wt = (z == 0) ? Wkvt : (z == 1) ? Wqt : (z == 2) ? Wpt : Wot;
    int N = (z == 0) ? 2048 : 1024;
    if (blockIdx.x * 32 >= N) return;
    int n0 = blockIdx.x * 32, k0 = blockIdx.y * 32;
    int x = threadIdx.x, y = threadIdx.y;
    for (int i = 0; i < 32; i += 8)
        tile[y + i][x] = W[(size_t)(k0 + y + i) * N + n0 + x];
    __syncthreads();
    for (int i = 0; i < 32; i += 8)
        Wt[(size_t)(n0 + y + i) * 1024 + k0 + x] = (bf16_t)tile[x][y + i];  // K == 1024 always
}

// ---------------- bf16 MFMA GEMM tile body (R3 padded-LDS staging) ----------------
// C(M,N) tile at (m0,n0): A(MxK) @ Bt(NxK)^T, K = 1024. Runtime epilogue:
// epi 0: bf16 store out0. epi 1: out0=acc+add0[n], out1=acc+add1[n] (bf16).
// epi 2: fp32 outf = acc + add0[m*N+n].
__device__ __forceinline__ void gemm_tile(
    const bf16_t* __restrict__ A, const bf16_t* __restrict__ Bt, int N,
    int m0, int n0, int epi,
    bf16_t* __restrict__ out0, bf16_t* __restrict__ out1,
    const float* __restrict__ add0, const float* __restrict__ add1,
    float* __restrict__ outf,
    bf16_t (*Al)[72], bf16_t (*Bl)[72]) {
    const int K = 1024;
    int tid = threadIdx.x;
    int wave = tid >> 6, lane = tid & 63, quad = lane >> 4, l16 = lane & 15;
    int wm = (wave & 1) * 64, wn = (wave >> 1) * 64;
    f32x4 zero = {0.f, 0.f, 0.f, 0.f};
    f32x4 acc[4][4];
    #pragma unroll
    for (int i = 0; i < 4; i++)
        #pragma unroll
        for (int j = 0; j < 4; j++) acc[i][j] = zero;

    for (int k0 = 0; k0 < K; k0 += 64) {
        __syncthreads();
        #pragma unroll
        for (int r = 0; r < 4; r++) {
            int idx = tid + 256 * r;
            int row = idx >> 3, seg = (idx & 7) * 8;
            *(uint4*)&Al[row][seg] = *(const uint4*)&A[(size_t)(m0 + row) * K + k0 + seg];
            *(uint4*)&Bl[row][seg] = *(const uint4*)&Bt[(size_t)(n0 + row) * K + k0 + seg];
        }
        __syncthreads();
        #pragma unroll
        for (int ks = 0; ks < 2; ks++) {
            bf16x8 af[4], bfr[4];
            #pragma unroll
            for (int i = 0; i < 4; i++)
                af[i] = *(const bf16x8*)&Al[wm + i * 16 + l16][ks * 32 + quad * 8];
            #pragma unroll
            for (int j = 0; j < 4; j++)
                bfr[j] = *(const bf16x8*)&Bl[wn + j * 16 + l16][ks * 32 + quad * 8];
            #pragma unroll
            for (int i = 0; i < 4; i++)
                #pragma unroll
                for (int j = 0; j < 4; j++) acc[i][j] = MFMA16(af[i], bfr[j], acc[i][j]);
        }
    }
    #pragma unroll
    for (int i = 0; i < 4; i++)
        #pragma unroll
        for (int j = 0; j < 4; j++)
            #pragma unroll
            for (int reg = 0; reg < 4; reg++) {
                int m = m0 + wm + i * 16 + quad * 4 + reg;
                int n = n0 + wn + j * 16 + l16;
                float v = acc[i][j][reg];
                if (epi == 0) {
                    out0[(size_t)m * N + n] = (bf16_t)v;
                } else if (epi == 1) {
                    out0[(size_t)m * N + n] = (bf16_t)(v + add0[n]);
                    out1[(size_t)m * N + n] = (bf16_t)(v + add1[n]);
                } else {
                    outf[(size_t)m * N + n] = v + add0[(size_t)m * N + n];
                }
            }
}

// ---------------- packed pre-attention GEMMs: kv | q(+u,+v dual) | p ----------------
// grid.x = 1024 + 256 + 128 = 1408 blocks of 128x128.
__global__ __launch_bounds__(256) void gemm3_kernel(
    const bf16_t* __restrict__ Xbf, const bf16_t* __restrict__ Wkvt, bf16_t* __restrict__ kvb,
    const bf16_t* __restrict__ Wqt, bf16_t* __restrict__ qub, bf16_t* __restrict__ qvb,
    const float* __restrict__ u, const float* __restrict__ v,
    const bf16_t* __restrict__ Pemb, const bf16_t* __restrict__ Wpt, bf16_t* __restrict__ pb) {
    __shared__ __attribute__((aligned(16))) bf16_t Al[128][72];
    __shared__ __attribute__((aligned(16))) bf16_t Bl[128][72];
    int id = blockIdx.x;
    if (id < 1024) {
        gemm_tile(Xbf, Wkvt, 2048, (id >> 4) * 128, (id & 15) * 128, 0,
                  kvb, nullptr, nullptr, nullptr, nullptr, Al, Bl);
    } else if (id < 1280) {
        int t = id - 1024;
        gemm_tile(Xbf + (size_t)P_ * B_ * E_, Wqt, 1024, (t >> 3) * 128, (t & 7) * 128, 1,
                  qub, qvb, u, v, nullptr, Al, Bl);
    } else {
        int t = id - 1280;
        gemm_tile(Pemb, Wpt, 1024, (t >> 3) * 128, (t & 7) * 128, 0,
                  pb, nullptr, nullptr, nullptr, nullptr, Al, Bl);
    }
}

// ---------------- output GEMM: opre = awv @ W_o + inputMHA (fp32) ----------------
__global__ __launch_bounds__(256) void gemmo_kernel(
    const bf16_t* __restrict__ awvb, const bf16_t* __restrict__ Wot,
    const float* __restrict__ inputMHA, float* __restrict__ opre) {
    __shared__ __attribute__((aligned(16))) bf16_t Al[128][72];
    __shared__ __attribute__((aligned(16))) bf16_t Bl[128][72];
    int id = blockIdx.x;
    gemm_tile(awvb, Wot, 1024, (id >> 3) * 128, (id & 7) * 128, 2,
              nullptr, nullptr, inputMHA, nullptr, opre, Al, Bl);
}

// ---------------- flash attention (R0-proven + T5 setprio): chunked split-j + atomic combine ----------------
__global__ __launch_bounds__(256) void flash_kernel(
    const bf16_t* __restrict__ qu, const bf16_t* __restrict__ qv,
    const bf16_t* __restrict__ kv, const bf16_t* __restrict__ pm,
    float* __restrict__ Oacc, float* __restrict__ lacc) {
    __shared__ __attribute__((aligned(16))) bf16_t Klds[64 * 64];
    __shared__ __attribute__((aligned(16))) bf16_t Vt[64 * 64];
    __shared__ __attribute__((aligned(16))) bf16_t Plds[128 * 64];   // ring
    __shared__ __attribute__((aligned(16))) bf16_t Prob[4 * 16 * 64];

    int tid = threadIdx.x;
    int wave = tid >> 6, lane = tid & 63, quad = lane >> 4, l16 = lane & 15;

    int x = blockIdx.x;
    int s_blk, c;
    if (x < 24) { s_blk = x / 3; c = x - s_blk * 3; }
    else        { int y = x - 24; s_blk = 8 + (y >> 2); c = y & 3; }
    int nt = 17 + s_blk;
    int t0 = c * 8;
    int t1 = t0 + 8; if (t1 > nt) t1 = nt;

    int s0 = s_blk * 64;
    int bh = blockIdx.y;
    int b = bh >> 4, h = bh & 15;
    int srow0 = s0 + wave * 16;

    const bf16_t* qub = qu + ((size_t)(srow0 + l16) * B_ + b) * 1024 + h * 64 + quad * 8;
    const bf16_t* qvb = qv + ((size_t)(srow0 + l16) * B_ + b) * 1024 + h * 64 + quad * 8;
    bf16x8 aqu0 = *(const bf16x8*)(qub);
    bf16x8 aqu1 = *(const bf16x8*)(qub + 32);
    bf16x8 aqv0 = *(const bf16x8*)(qvb);
    bf16x8 aqv1 = *(const bf16x8*)(qvb + 32);

    f32x4 zero = {0.f, 0.f, 0.f, 0.f};
    f32x4 accO[4];
    #pragma unroll
    for (int ot = 0; ot < 4; ot++) accO[ot] = zero;
    float lrowp[4] = {0.f, 0.f, 0.f, 0.f};

    const int w0u = 960 - s0;
    const int woff = 48 - wave * 16;
    const float SCL = 0.125f * 1.44269504088896f;

    int jr = tid >> 3, seg8g = tid & 7;
    int jp = tid & 31, iseg = tid >> 5;
    uint* VtU = (uint*)&Vt[0];
    bf16_t* ProbW = Prob + (wave << 10);

    {
        int j0 = t0 * 64;
        const bf16_t* kp = kv + ((size_t)(j0 + jr) * B_ + b) * 2048 + h * 64 + seg8g * 8;
        uint4 ka = *(const uint4*)kp;
        uint4 kb = *(const uint4*)(kp + (size_t)32 * B_ * 2048);
        const bf16_t* vp = kv + ((size_t)(j0 + jp * 2) * B_ + b) * 2048 + 1024 + h * 64 + iseg * 8;
        u16x8 va = *(const u16x8*)vp;
        u16x8 vb = *(const u16x8*)(vp + (size_t)B_ * 2048);
        uint4 pd[4];
        #pragma unroll
        for (int r = 0; r < 4; r++) {
            int idx = tid + 256 * r;
            int pr = idx >> 3, pg = idx & 7;
            int lr = w0u + j0 + pr; if (lr > J_ - 1) lr = J_ - 1;
            pd[r] = *(const uint4*)(pm + (size_t)lr * 1024 + h * 64 + pg * 8);
        }
        *(uint4*)&Klds[SWZ(jr, seg8g * 8)] = ka;
        *(uint4*)&Klds[SWZ(jr + 32, seg8g * 8)] = kb;
        #pragma unroll
        for (int e = 0; e < 8; e++) {
            int row = iseg * 8 + e;
            VtU[(row << 5) + ((((jp >> 2) ^ (row & 7)) << 2)) + (jp & 3)] =
                (uint)va[e] | ((uint)vb[e] << 16);
        }
        #pragma unroll
        for (int r = 0; r < 4; r++) {
            int idx = tid + 256 * r;
            int pr = idx >> 3, pg = idx & 7;
            *(uint4*)&Plds[SWZ((w0u + j0 + pr) & 127, pg * 8)] = pd[r];
        }
    }
    __syncthreads();

    for (int it = t0; it < t1; it++) {
        int j0 = it * 64;
        bool pf = (it + 1 < t1);
        uint4 ka, kb, pd0, pd1;
        u16x8 va, vb;
        int pr0 = tid >> 3, pg0 = tid & 7;
        int pr1 = (tid + 256) >> 3, pg1 = tid & 7;
        if (pf) {
            int j1 = j0 + 64;
            const bf16_t* kp = kv + ((size_t)(j1 + jr) * B_ + b) * 2048 + h * 64 + seg8g * 8;
            ka = *(const uint4*)kp;
            kb = *(const uint4*)(kp + (size_t)32 * B_ * 2048);
            const bf16_t* vp = kv + ((size_t)(j1 + jp * 2) * B_ + b) * 2048 + 1024 + h * 64 + iseg * 8;
            va = *(const u16x8*)vp;
            vb = *(const u16x8*)(vp + (size_t)B_ * 2048);
            int lr0 = w0u + j0 + 128 + pr0; if (lr0 > J_ - 1) lr0 = J_ - 1;
            int lr1 = w0u + j0 + 128 + pr1; if (lr1 > J_ - 1) lr1 = J_ - 1;
            pd0 = *(const uint4*)(pm + (size_t)lr0 * 1024 + h * 64 + pg0 * 8);
            pd1 = *(const uint4*)(pm + (size_t)lr1 * 1024 + h * 64 + pg1 * 8);
        }

        f32x4 cs[4];
        #pragma unroll
        for (int t = 0; t < 4; t++) cs[t] = zero;
        __builtin_amdgcn_s_setprio(1);
        #pragma unroll
        for (int ks = 0; ks < 2; ks++) {
            bf16x8 aq = ks ? aqu1 : aqu0;
            #pragma unroll
            for (int t = 0; t < 4; t++) {
                bf16x8 bk = *(const bf16x8*)&Klds[SWZ(t * 16 + l16, ks * 32 + quad * 8)];
                cs[t] = MFMA16(aq, bk, cs[t]);
            }
        }
        f32x4 ep[5];
        #pragma unroll
        for (int t = 0; t < 5; t++) ep[t] = zero;
        #pragma unroll
        for (int ks = 0; ks < 2; ks++) {
            bf16x8 aq = ks ? aqv1 : aqv0;
            #pragma unroll
            for (int t = 0; t < 5; t++) {
                int prow = (w0u + j0 + woff + t * 16 + l16) & 127;
                bf16x8 bp = *(const bf16x8*)&Plds[SWZ(prow, ks * 32 + quad * 8)];
                ep[t] = MFMA16(aq, bp, ep[t]);
            }
        }
        __builtin_amdgcn_s_setprio(0);

        #pragma unroll
        for (int reg = 0; reg < 4; reg++) {
            int r = quad * 4 + reg;
            int s = srow0 + r;
            int idx = l16 + 15 - r;
            int srcl = quad * 16 + (idx & 15);
            float sh[5];
            #pragma unroll
            for (int t = 0; t < 5; t++) sh[t] = __shfl(ep[t][reg], srcl);
            float psum = 0.f;
            #pragma unroll
            for (int t = 0; t < 4; t++) {
                float pos = (idx < 16) ? sh[t] : sh[t + 1];
                float p = exp2f((cs[t][reg] + pos) * SCL);
                p = (j0 + t * 16 + l16 > P_ + s) ? 0.f : p;
                ProbW[SWZ(r, t * 16 + l16)] = (bf16_t)p;
                psum += p;
            }
            lrowp[reg] += psum;
        }

        __builtin_amdgcn_s_setprio(1);
        #pragma unroll
        for (int ks = 0; ks < 2; ks++) {
            bf16x8 pa = *(const bf16x8*)&Prob[(wave << 10) + SWZ(l16, ks * 32 + quad * 8)];
            #pragma unroll
            for (int ot = 0; ot < 4; ot++) {
                bf16x8 bv = *(const bf16x8*)&Vt[SWZ(ot * 16 + l16, ks * 32 + quad * 8)];
                accO[ot] = MFMA16(pa, bv, accO[ot]);
            }
        }
        __builtin_amdgcn_s_setprio(0);

        __syncthreads();
        if (pf) {
            *(uint4*)&Klds[SWZ(jr, seg8g * 8)] = ka;
            *(uint4*)&Klds[SWZ(jr + 32, seg8g * 8)] = kb;
            #pragma unroll
            for (int e2 = 0; e2 < 8; e2++) {
                int row = iseg * 8 + e2;
                VtU[(row << 5) + ((((jp >> 2) ^ (row & 7)) << 2)) + (jp & 3)] =
                    (uint)va[e2] | ((uint)vb[e2] << 16);
            }
            *(uint4*)&Plds[SWZ((w0u + j0 + pr0) & 127, pg0 * 8)] = pd0;
            *(uint4*)&Plds[SWZ((w0u + j0 + pr1) & 127, pg1 * 8)] = pd1;
        }
        __syncthreads();
    }

    #pragma unroll
    for (int reg = 0; reg < 4; reg++) {
        int r = quad * 4 + reg;
        int srow = srow0 + r;
        float l = lrowp[reg];
        #pragma unroll
        for (int d = 1; d < 16; d <<= 1) l += __shfl_xor(l, d);
        if (l16 == 0) atomicAdd(&lacc[((size_t)srow * B_ + b) * H_ + h], l);
        size_t rowoff = ((size_t)srow * B_ + b) * 1024 + h * 64;
        #pragma unroll
        for (int ot = 0; ot < 4; ot++)
            atomicAdd(&Oacc[rowoff + ot * 16 + l16], accO[ot][reg]);
    }
}

// ---------------- combine/normalize: awv = Oacc / lacc ----------------
__global__ __launch_bounds__(256) void norm_kernel(const float* __restrict__ Oacc,
                                                   const float* __restrict__ lacc,
                                                   bf16_t* __restrict__ awv) {
    int i4 = (blockIdx.x * 256 + threadIdx.x) * 4;
    int row = i4 >> 6;
    float inv = 1.0f / lacc[row];
    float4 o = *(const float4*)(Oacc + i4);
    bf16x4 r = {(bf16_t)(o.x * inv), (bf16_t)(o.y * inv),
                (bf16_t)(o.z * inv), (bf16_t)(o.w * inv)};
    *(bf16x4*)(awv + i4) = r;
}

// ---------------- LayerNorm over E=1024 ----------------
__global__ __launch_bounds__(256) void ln_kernel(const float* __restrict__ x,
                                                 const float* __restrict__ gamma,
                                                 const float* __restrict__ beta,
                                                 float* __restrict__ out) {
    int row = blockIdx.x, tid = threadIdx.x;
    int lane = tid & 63, wave = tid >> 6;
    float4 v = ((const float4*)(x + (size_t)row * 1024))[tid];
    float s = v.x + v.y + v.z + v.w;
    float ss = v.x * v.x + v.y * v.y + v.z * v.z + v.w * v.w;
    #pragma unroll
    for (int sh = 1; sh < 64; sh <<= 1) { s += __shfl_xor(s, sh); ss += __shfl_xor(ss, sh); }
    __shared__ float red[8];
    if (lane == 0) { red[wave] = s; red[4 + wave] = ss; }
    __syncthreads();
    s = red[0] + red[1] + red[2] + red[3];
    ss = red[4] + red[5] + red[6] + red[7];
    float mean = s * (1.f / 1024.f);
    float var = ss * (1.f / 1024.f) - mean * mean;
    float inv = rsqrtf(var + 1e-5f);
    float4 g = ((const float4*)gamma)[tid];
    float4 bt = ((const float4*)beta)[tid];
    float4 o;
    o.x = (v.x - mean) * inv * g.x + bt.x;
    o.y = (v.y - mean) * inv * g.y + bt.y;
    o.z = (v.z - mean) * inv * g.z + bt.z;
    o.w = (v.w - mean) * inv * g.w + bt.w;
    ((float4*)(out + (size_t)row * 1024))[tid] = o;
}

extern "C" void kernel_launch(void* const* d_in, const int* in_sizes, int n_in,
                              void* d_out, int out_size, void* d_ws, size_t ws_size,
                              hipStream_t stream) {
    const float* inputMHA = (const float*)d_in[0];
    const float* posEmb   = (const float*)d_in[1];
    const float* memory   = (const float*)d_in[2];
    const float* u        = (const float*)d_in[3];
    const float* v        = (const float*)d_in[4];
    const float* W_kv     = (const float*)d_in[6];
    const float* W_q      = (const float*)d_in[7];
    const float* W_p      = (const float*)d_in[8];
    const float* W_o      = (const float*)d_in[9];
    const float* gamma    = (const float*)d_in[10];
    const float* beta     = (const float*)d_in[11];
    float* out = (float*)d_out;

    char* ws = (char*)d_ws;
    size_t off = 0;
    auto alloc = [&](size_t bytes) -> void* {
        void* p = ws + off;
        off += (bytes + 255) & ~(size_t)255;
        return p;
    };
    bf16_t* Xbf  = (bf16_t*)alloc((size_t)J_ * B_ * E_ * 2);
    bf16_t* Wkvt = (bf16_t*)alloc((size_t)2048 * 1024 * 2);
    bf16_t* Wqt  = (bf16_t*)alloc((size_t)1024 * 1024 * 2);
    bf16_t* Wpt  = (bf16_t*)alloc((size_t)1024 * 1024 * 2);
    bf16_t* Wot  = (bf16_t*)alloc((size_t)1024 * 1024 * 2);
    bf16_t* Pemb = (bf16_t*)alloc((size_t)2048 * 1024 * 2);
    bf16_t* kvb  = (bf16_t*)alloc((size_t)8192 * 2048 * 2);
    bf16_t* qub  = (bf16_t*)alloc((size_t)4096 * 1024 * 2);
    bf16_t* qvb  = (bf16_t*)alloc((size_t)4096 * 1024 * 2);
    bf16_t* pb   = (bf16_t*)alloc((size_t)2048 * 1024 * 2);
    bf16_t* awvb = (bf16_t*)alloc((size_t)4096 * 1024 * 2);
    float*  opre = (float*)alloc((size_t)4096 * 1024 * 4);
    float*  Oacc = (float*)alloc((size_t)4096 * 1024 * 4);
    float*  lacc = (float*)alloc((size_t)S_ * B_ * H_ * 4);

    hipMemsetAsync(Oacc, 0, (size_t)4096 * 1024 * 4, stream);
    hipMemsetAsync(lacc, 0, (size_t)S_ * B_ * H_ * 4, stream);

    cvt_all_kernel<<<10240, 256, 0, stream>>>(memory, inputMHA, posEmb, Xbf, Pemb);
    trans_all_kernel<<<dim3(64, 32, 4), dim3(32, 8), 0, stream>>>(
        W_kv, Wkvt, W_q, Wqt, W_p, Wpt, W_o, Wot);

    gemm3_kernel<<<1408, 256, 0, stream>>>(Xbf, Wkvt, kvb, Wqt, qub, qvb, u, v, Pemb, Wpt, pb);

    flash_kernel<<<dim3(56, B_ * H_), 256, 0, stream>>>(qub, qvb, kvb, pb, Oacc, lacc);
    norm_kernel<<<4096, 256, 0, stream>>>(Oacc, lacc, awvb);

    gemmo_kernel<<<256, 256, 0, stream>>>(awvb, Wot, inputMHA, opre);
    ln_kernel<<<S_ * B_, 256, 0, stream>>>(opre, gamma, beta, out);
}

// Round 7
// 433.011 us; speedup vs baseline: 1.5739x; 1.0040x over previous
//
#include <hip/hip_runtime.h>
#include <hip/hip_bf16.h>

#define S_ 1024
#define P_ 1024
#define B_ 4
#define E_ 1024
#define J_ 2048
#define H_ 16
#define I_ 64

typedef __bf16 bf16_t;
typedef __bf16 bf16x8 __attribute__((ext_vector_type(8)));
typedef __bf16 bf16x4 __attribute__((ext_vector_type(4)));
typedef unsigned short u16x8 __attribute__((ext_vector_type(8)));
typedef float f32x4 __attribute__((ext_vector_type(4)));

#define MFMA16(a, b, c) __builtin_amdgcn_mfma_f32_16x16x32_bf16(a, b, c, 0, 0, 0)

// XOR-granule swizzle for stride-64 bf16 LDS tiles (flash + gemm).
#define SWZ(r, c) (((r) << 6) + ((((((c) >> 3)) ^ ((r) & 7)) << 3)) + ((c) & 7))

// async global->LDS 16B/lane; LDS dest is wave-uniform base + lane*16 (linear).
__device__ __forceinline__ void g2l16(const bf16_t* g, bf16_t* l) {
    __builtin_amdgcn_global_load_lds(
        (const __attribute__((address_space(1))) unsigned int*)(const void*)g,
        (__attribute__((address_space(3))) unsigned int*)(void*)l,
        16, 0, 0);
}

// ---------------- fused fp32 -> bf16 converts (memory, inputMHA, posEmb) ----------------
__global__ __launch_bounds__(256) void cvt_all_kernel(const float* __restrict__ memory,
                                                      const float* __restrict__ input,
                                                      const float* __restrict__ posEmb,
                                                      bf16_t* __restrict__ Xbf,
                                                      bf16_t* __restrict__ Pemb) {
    // segments: [0,4096) memory->Xbf, [4096,8192) input->Xbf+P*B*E, [8192,10240) posEmb->Pemb
    int blk = blockIdx.x;
    const float* src;
    bf16_t* dst;
    if (blk < 4096) { src = memory; dst = Xbf; }
    else if (blk < 8192) { blk -= 4096; src = input; dst = Xbf + (size_t)P_ * B_ * E_; }
    else { blk -= 8192; src = posEmb; dst = Pemb; }
    int i = (blk * 256 + threadIdx.x) * 4;
    float4 v = *(const float4*)(src + i);
    bf16x4 o = {(bf16_t)v.x, (bf16_t)v.y, (bf16_t)v.z, (bf16_t)v.w};
    *(bf16x4*)(dst + i) = o;
}

// ---------------- fused weight transposes: W (K x N) fp32 -> W^T (N x K) bf16 ----------------
__global__ void trans_all_kernel(const float* __restrict__ W_kv, bf16_t* __restrict__ Wkvt,
                                 const float* __restrict__ W_q, bf16_t* __restrict__ Wqt,
                                 const float* __restrict__ W_p, bf16_t* __restrict__ Wpt,
                                 const float* __restrict__ W_o, bf16_t* __restrict__ Wot) {
    __shared__ float tile[32][33];
    int z = blockIdx.z;
    const float* W = (z == 0) ? W_kv : (z == 1) ? W_q : (z == 2) ? W_p : W_o;
    bf16_t* Wt = (z == 0) ? Wkvt : (z == 1) ? Wqt : (z == 2) ? Wpt : Wot;
    int N = (z == 0) ? 2048 : 1024;
    if (blockIdx.x * 32 >= N) return;
    int n0 = blockIdx.x * 32, k0 = blockIdx.y * 32;
    int x = threadIdx.x, y = threadIdx.y;
    for (int i = 0; i < 32; i += 8)
        tile[y + i][x] = W[(size_t)(k0 + y + i) * N + n0 + x];
    __syncthreads();
    for (int i = 0; i < 32; i += 8)
        Wt[(size_t)(n0 + y + i) * 1024 + k0 + x] = (bf16_t)tile[x][y + i];  // K == 1024 always
}

// ---------------- bf16 MFMA GEMM tile body (R7: global_load_lds + SWZ LDS) ----------------
// C(M,N) tile at (m0,n0): A(MxK) @ Bt(NxK)^T, K = 1024. LDS is LINEAR [128*64]
// with XOR-granule content: LDS[row][g] holds source granule g^(row&7) (achieved by
// pre-swizzling the per-lane GLOBAL address; global_load_lds dest must be linear).
// Reads use SWZ() — the same proven bank-conflict-free pattern as flash's Klds.
// epi 0: bf16 store out0. epi 1: out0=acc+add0[n], out1=acc+add1[n] (bf16).
// epi 2: fp32 outf = acc + add0[m*N+n].
__device__ __forceinline__ void gemm_tile(
    const bf16_t* __restrict__ A, const bf16_t* __restrict__ Bt, int N,
    int m0, int n0, int epi,
    bf16_t* __restrict__ out0, bf16_t* __restrict__ out1,
    const float* __restrict__ add0, const float* __restrict__ add1,
    float* __restrict__ outf,
    bf16_t* AlL, bf16_t* BlL) {
    const int K = 1024;
    int tid = threadIdx.x;
    int wave = tid >> 6, lane = tid & 63, quad = lane >> 4, l16 = lane & 15;
    int wm = (wave & 1) * 64, wn = (wave >> 1) * 64;
    int lrow = lane >> 3;                 // row-within-8 this lane stages
    int gsw = ((lane & 7) ^ lrow) << 3;   // pre-swizzled source granule offset (elems)
    f32x4 zero = {0.f, 0.f, 0.f, 0.f};
    f32x4 acc[4][4];
    #pragma unroll
    for (int i = 0; i < 4; i++)
        #pragma unroll
        for (int j = 0; j < 4; j++) acc[i][j] = zero;

    for (int k0 = 0; k0 < K; k0 += 64) {
        __syncthreads();
        #pragma unroll
        for (int r = 0; r < 4; r++) {
            int row0 = r * 32 + wave * 8;     // wave-uniform base row (8 rows/issue)
            g2l16(&A[(size_t)(m0 + row0 + lrow) * K + k0 + gsw], &AlL[row0 * 64]);
            g2l16(&Bt[(size_t)(n0 + row0 + lrow) * K + k0 + gsw], &BlL[row0 * 64]);
        }
        __syncthreads();   // compiler drains vmcnt before this barrier
        #pragma unroll
        for (int ks = 0; ks < 2; ks++) {
            bf16x8 af[4], bfr[4];
            #pragma unroll
            for (int i = 0; i < 4; i++)
                af[i] = *(const bf16x8*)&AlL[SWZ(wm + i * 16 + l16, ks * 32 + quad * 8)];
            #pragma unroll
            for (int j = 0; j < 4; j++)
                bfr[j] = *(const bf16x8*)&BlL[SWZ(wn + j * 16 + l16, ks * 32 + quad * 8)];
            #pragma unroll
            for (int i = 0; i < 4; i++)
                #pragma unroll
                for (int j = 0; j < 4; j++) acc[i][j] = MFMA16(af[i], bfr[j], acc[i][j]);
        }
    }
    #pragma unroll
    for (int i = 0; i < 4; i++)
        #pragma unroll
        for (int j = 0; j < 4; j++)
            #pragma unroll
            for (int reg = 0; reg < 4; reg++) {
                int m = m0 + wm + i * 16 + quad * 4 + reg;
                int n = n0 + wn + j * 16 + l16;
                float v = acc[i][j][reg];
                if (epi == 0) {
                    out0[(size_t)m * N + n] = (bf16_t)v;
                } else if (epi == 1) {
                    out0[(size_t)m * N + n] = (bf16_t)(v + add0[n]);
                    out1[(size_t)m * N + n] = (bf16_t)(v + add1[n]);
                } else {
                    outf[(size_t)m * N + n] = v + add0[(size_t)m * N + n];
                }
            }
}

// ---------------- packed pre-attention GEMMs: kv | q(+u,+v dual) | p ----------------
// grid.x = 1024 + 256 + 128 = 1408 blocks of 128x128.
__global__ __launch_bounds__(256) void gemm3_kernel(
    const bf16_t* __restrict__ Xbf, const bf16_t* __restrict__ Wkvt, bf16_t* __restrict__ kvb,
    const bf16_t* __restrict__ Wqt, bf16_t* __restrict__ qub, bf16_t* __restrict__ qvb,
    const float* __restrict__ u, const float* __restrict__ v,
    const bf16_t* __restrict__ Pemb, const bf16_t* __restrict__ Wpt, bf16_t* __restrict__ pb) {
    __shared__ __attribute__((aligned(16))) bf16_t Al[128 * 64];
    __shared__ __attribute__((aligned(16))) bf16_t Bl[128 * 64];
    int id = blockIdx.x;
    if (id < 1024) {
        gemm_tile(Xbf, Wkvt, 2048, (id >> 4) * 128, (id & 15) * 128, 0,
                  kvb, nullptr, nullptr, nullptr, nullptr, Al, Bl);
    } else if (id < 1280) {
        int t = id - 1024;
        gemm_tile(Xbf + (size_t)P_ * B_ * E_, Wqt, 1024, (t >> 3) * 128, (t & 7) * 128, 1,
                  qub, qvb, u, v, nullptr, Al, Bl);
    } else {
        int t = id - 1280;
        gemm_tile(Pemb, Wpt, 1024, (t >> 3) * 128, (t & 7) * 128, 0,
                  pb, nullptr, nullptr, nullptr, nullptr, Al, Bl);
    }
}

// ---------------- output GEMM: opre = awv @ W_o + inputMHA (fp32) ----------------
__global__ __launch_bounds__(256) void gemmo_kernel(
    const bf16_t* __restrict__ awvb, const bf16_t* __restrict__ Wot,
    const float* __restrict__ inputMHA, float* __restrict__ opre) {
    __shared__ __attribute__((aligned(16))) bf16_t Al[128 * 64];
    __shared__ __attribute__((aligned(16))) bf16_t Bl[128 * 64];
    int id = blockIdx.x;
    gemm_tile(awvb, Wot, 1024, (id >> 3) * 128, (id & 7) * 128, 2,
              nullptr, nullptr, inputMHA, nullptr, opre, Al, Bl);
}

// ---------------- flash attention (R0-proven + T5 setprio): chunked split-j + atomic combine ----------------
__global__ __launch_bounds__(256) void flash_kernel(
    const bf16_t* __restrict__ qu, const bf16_t* __restrict__ qv,
    const bf16_t* __restrict__ kv, const bf16_t* __restrict__ pm,
    float* __restrict__ Oacc, float* __restrict__ lacc) {
    __shared__ __attribute__((aligned(16))) bf16_t Klds[64 * 64];
    __shared__ __attribute__((aligned(16))) bf16_t Vt[64 * 64];
    __shared__ __attribute__((aligned(16))) bf16_t Plds[128 * 64];   // ring
    __shared__ __attribute__((aligned(16))) bf16_t Prob[4 * 16 * 64];

    int tid = threadIdx.x;
    int wave = tid >> 6, lane = tid & 63, quad = lane >> 4, l16 = lane & 15;

    int x = blockIdx.x;
    int s_blk, c;
    if (x < 24) { s_blk = x / 3; c = x - s_blk * 3; }
    else        { int y = x - 24; s_blk = 8 + (y >> 2); c = y & 3; }
    int nt = 17 + s_blk;
    int t0 = c * 8;
    int t1 = t0 + 8; if (t1 > nt) t1 = nt;

    int s0 = s_blk * 64;
    int bh = blockIdx.y;
    int b = bh >> 4, h = bh & 15;
    int srow0 = s0 + wave * 16;

    const bf16_t* qub = qu + ((size_t)(srow0 + l16) * B_ + b) * 1024 + h * 64 + quad * 8;
    const bf16_t* qvb = qv + ((size_t)(srow0 + l16) * B_ + b) * 1024 + h * 64 + quad * 8;
    bf16x8 aqu0 = *(const bf16x8*)(qub);
    bf16x8 aqu1 = *(const bf16x8*)(qub + 32);
    bf16x8 aqv0 = *(const bf16x8*)(qvb);
    bf16x8 aqv1 = *(const bf16x8*)(qvb + 32);

    f32x4 zero = {0.f, 0.f, 0.f, 0.f};
    f32x4 accO[4];
    #pragma unroll
    for (int ot = 0; ot < 4; ot++) accO[ot] = zero;
    float lrowp[4] = {0.f, 0.f, 0.f, 0.f};

    const int w0u = 960 - s0;
    const int woff = 48 - wave * 16;
    const float SCL = 0.125f * 1.44269504088896f;

    int jr = tid >> 3, seg8g = tid & 7;
    int jp = tid & 31, iseg = tid >> 5;
    uint* VtU = (uint*)&Vt[0];
    bf16_t* ProbW = Prob + (wave << 10);

    {
        int j0 = t0 * 64;
        const bf16_t* kp = kv + ((size_t)(j0 + jr) * B_ + b) * 2048 + h * 64 + seg8g * 8;
        uint4 ka = *(const uint4*)kp;
        uint4 kb = *(const uint4*)(kp + (size_t)32 * B_ * 2048);
        const bf16_t* vp = kv + ((size_t)(j0 + jp * 2) * B_ + b) * 2048 + 1024 + h * 64 + iseg * 8;
        u16x8 va = *(const u16x8*)vp;
        u16x8 vb = *(const u16x8*)(vp + (size_t)B_ * 2048);
        uint4 pd[4];
        #pragma unroll
        for (int r = 0; r < 4; r++) {
            int idx = tid + 256 * r;
            int pr = idx >> 3, pg = idx & 7;
            int lr = w0u + j0 + pr; if (lr > J_ - 1) lr = J_ - 1;
            pd[r] = *(const uint4*)(pm + (size_t)lr * 1024 + h * 64 + pg * 8);
        }
        *(uint4*)&Klds[SWZ(jr, seg8g * 8)] = ka;
        *(uint4*)&Klds[SWZ(jr + 32, seg8g * 8)] = kb;
        #pragma unroll
        for (int e = 0; e < 8; e++) {
            int row = iseg * 8 + e;
            VtU[(row << 5) + ((((jp >> 2) ^ (row & 7)) << 2)) + (jp & 3)] =
                (uint)va[e] | ((uint)vb[e] << 16);
        }
        #pragma unroll
        for (int r = 0; r < 4; r++) {
            int idx = tid + 256 * r;
            int pr = idx >> 3, pg = idx & 7;
            *(uint4*)&Plds[SWZ((w0u + j0 + pr) & 127, pg * 8)] = pd[r];
        }
    }
    __syncthreads();

    for (int it = t0; it < t1; it++) {
        int j0 = it * 64;
        bool pf = (it + 1 < t1);
        uint4 ka, kb, pd0, pd1;
        u16x8 va, vb;
        int pr0 = tid >> 3, pg0 = tid & 7;
        int pr1 = (tid + 256) >> 3, pg1 = tid & 7;
        if (pf) {
            int j1 = j0 + 64;
            const bf16_t* kp = kv + ((size_t)(j1 + jr) * B_ + b) * 2048 + h * 64 + seg8g * 8;
            ka = *(const uint4*)kp;
            kb = *(const uint4*)(kp + (size_t)32 * B_ * 2048);
            const bf16_t* vp = kv + ((size_t)(j1 + jp * 2) * B_ + b) * 2048 + 1024 + h * 64 + iseg * 8;
            va = *(const u16x8*)vp;
            vb = *(const u16x8*)(vp + (size_t)B_ * 2048);
            int lr0 = w0u + j0 + 128 + pr0; if (lr0 > J_ - 1) lr0 = J_ - 1;
            int lr1 = w0u + j0 + 128 + pr1; if (lr1 > J_ - 1) lr1 = J_ - 1;
            pd0 = *(const uint4*)(pm + (size_t)lr0 * 1024 + h * 64 + pg0 * 8);
            pd1 = *(const uint4*)(pm + (size_t)lr1 * 1024 + h * 64 + pg1 * 8);
        }

        f32x4 cs[4];
        #pragma unroll
        for (int t = 0; t < 4; t++) cs[t] = zero;
        __builtin_amdgcn_s_setprio(1);
        #pragma unroll
        for (int ks = 0; ks < 2; ks++) {
            bf16x8 aq = ks ? aqu1 : aqu0;
            #pragma unroll
            for (int t = 0; t < 4; t++) {
                bf16x8 bk = *(const bf16x8*)&Klds[SWZ(t * 16 + l16, ks * 32 + quad * 8)];
                cs[t] = MFMA16(aq, bk, cs[t]);
            }
        }
        f32x4 ep[5];
        #pragma unroll
        for (int t = 0; t < 5; t++) ep[t] = zero;
        #pragma unroll
        for (int ks = 0; ks < 2; ks++) {
            bf16x8 aq = ks ? aqv1 : aqv0;
            #pragma unroll
            for (int t = 0; t < 5; t++) {
                int prow = (w0u + j0 + woff + t * 16 + l16) & 127;
                bf16x8 bp = *(const bf16x8*)&Plds[SWZ(prow, ks * 32 + quad * 8)];
                ep[t] = MFMA16(aq, bp, ep[t]);
            }
        }
        __builtin_amdgcn_s_setprio(0);

        #pragma unroll
        for (int reg = 0; reg < 4; reg++) {
            int r = quad * 4 + reg;
            int s = srow0 + r;
            int idx = l16 + 15 - r;
            int srcl = quad * 16 + (idx & 15);
            float sh[5];
            #pragma unroll
            for (int t = 0; t < 5; t++) sh[t] = __shfl(ep[t][reg], srcl);
            float psum = 0.f;
            #pragma unroll
            for (int t = 0; t < 4; t++) {
                float pos = (idx < 16) ? sh[t] : sh[t + 1];
                float p = exp2f((cs[t][reg] + pos) * SCL);
                p = (j0 + t * 16 + l16 > P_ + s) ? 0.f : p;
                ProbW[SWZ(r, t * 16 + l16)] = (bf16_t)p;
                psum += p;
            }
            lrowp[reg] += psum;
        }

        __builtin_amdgcn_s_setprio(1);
        #pragma unroll
        for (int ks = 0; ks < 2; ks++) {
            bf16x8 pa = *(const bf16x8*)&Prob[(wave << 10) + SWZ(l16, ks * 32 + quad * 8)];
            #pragma unroll
            for (int ot = 0; ot < 4; ot++) {
                bf16x8 bv = *(const bf16x8*)&Vt[SWZ(ot * 16 + l16, ks * 32 + quad * 8)];
                accO[ot] = MFMA16(pa, bv, accO[ot]);
            }
        }
        __builtin_amdgcn_s_setprio(0);

        __syncthreads();
        if (pf) {
            *(uint4*)&Klds[SWZ(jr, seg8g * 8)] = ka;
            *(uint4*)&Klds[SWZ(jr + 32, seg8g * 8)] = kb;
            #pragma unroll
            for (int e2 = 0; e2 < 8; e2++) {
                int row = iseg * 8 + e2;
                VtU[(row << 5) + ((((jp >> 2) ^ (row & 7)) << 2)) + (jp & 3)] =
                    (uint)va[e2] | ((uint)vb[e2] << 16);
            }
            *(uint4*)&Plds[SWZ((w0u + j0 + pr0) & 127, pg0 * 8)] = pd0;
            *(uint4*)&Plds[SWZ((w0u + j0 + pr1) & 127, pg1 * 8)] = pd1;
        }
        __syncthreads();
    }

    #pragma unroll
    for (int reg = 0; reg < 4; reg++) {
        int r = quad * 4 + reg;
        int srow = srow0 + r;
        float l = lrowp[reg];
        #pragma unroll
        for (int d = 1; d < 16; d <<= 1) l += __shfl_xor(l, d);
        if (l16 == 0) atomicAdd(&lacc[((size_t)srow * B_ + b) * H_ + h], l);
        size_t rowoff = ((size_t)srow * B_ + b) * 1024 + h * 64;
        #pragma unroll
        for (int ot = 0; ot < 4; ot++)
            atomicAdd(&Oacc[rowoff + ot * 16 + l16], accO[ot][reg]);
    }
}

// ---------------- combine/normalize: awv = Oacc / lacc ----------------
__global__ __launch_bounds__(256) void norm_kernel(const float* __restrict__ Oacc,
                                                   const float* __restrict__ lacc,
                                                   bf16_t* __restrict__ awv) {
    int i4 = (blockIdx.x * 256 + threadIdx.x) * 4;
    int row = i4 >> 6;
    float inv = 1.0f / lacc[row];
    float4 o = *(const float4*)(Oacc + i4);
    bf16x4 r = {(bf16_t)(o.x * inv), (bf16_t)(o.y * inv),
                (bf16_t)(o.z * inv), (bf16_t)(o.w * inv)};
    *(bf16x4*)(awv + i4) = r;
}

// ---------------- LayerNorm over E=1024 ----------------
__global__ __launch_bounds__(256) void ln_kernel(const float* __restrict__ x,
                                                 const float* __restrict__ gamma,
                                                 const float* __restrict__ beta,
                                                 float* __restrict__ out) {
    int row = blockIdx.x, tid = threadIdx.x;
    int lane = tid & 63, wave = tid >> 6;
    float4 v = ((const float4*)(x + (size_t)row * 1024))[tid];
    float s = v.x + v.y + v.z + v.w;
    float ss = v.x * v.x + v.y * v.y + v.z * v.z + v.w * v.w;
    #pragma unroll
    for (int sh = 1; sh < 64; sh <<= 1) { s += __shfl_xor(s, sh); ss += __shfl_xor(ss, sh); }
    __shared__ float red[8];
    if (lane == 0) { red[wave] = s; red[4 + wave] = ss; }
    __syncthreads();
    s = red[0] + red[1] + red[2] + red[3];
    ss = red[4] + red[5] + red[6] + red[7];
    float mean = s * (1.f / 1024.f);
    float var = ss * (1.f / 1024.f) - mean * mean;
    float inv = rsqrtf(var + 1e-5f);
    float4 g = ((const float4*)gamma)[tid];
    float4 bt = ((const float4*)beta)[tid];
    float4 o;
    o.x = (v.x - mean) * inv * g.x + bt.x;
    o.y = (v.y - mean) * inv * g.y + bt.y;
    o.z = (v.z - mean) * inv * g.z + bt.z;
    o.w = (v.w - mean) * inv * g.w + bt.w;
    ((float4*)(out + (size_t)row * 1024))[tid] = o;
}

extern "C" void kernel_launch(void* const* d_in, const int* in_sizes, int n_in,
                              void* d_out, int out_size, void* d_ws, size_t ws_size,
                              hipStream_t stream) {
    const float* inputMHA = (const float*)d_in[0];
    const float* posEmb   = (const float*)d_in[1];
    const float* memory   = (const float*)d_in[2];
    const float* u        = (const float*)d_in[3];
    const float* v        = (const float*)d_in[4];
    const float* W_kv     = (const float*)d_in[6];
    const float* W_q      = (const float*)d_in[7];
    const float* W_p      = (const float*)d_in[8];
    const float* W_o      = (const float*)d_in[9];
    const float* gamma    = (const float*)d_in[10];
    const float* beta     = (const float*)d_in[11];
    float* out = (float*)d_out;

    char* ws = (char*)d_ws;
    size_t off = 0;
    auto alloc = [&](size_t bytes) -> void* {
        void* p = ws + off;
        off += (bytes + 255) & ~(size_t)255;
        return p;
    };
    bf16_t* Xbf  = (bf16_t*)alloc((size_t)J_ * B_ * E_ * 2);
    bf16_t* Wkvt = (bf16_t*)alloc((size_t)2048 * 1024 * 2);
    bf16_t* Wqt  = (bf16_t*)alloc((size_t)1024 * 1024 * 2);
    bf16_t* Wpt  = (bf16_t*)alloc((size_t)1024 * 1024 * 2);
    bf16_t* Wot  = (bf16_t*)alloc((size_t)1024 * 1024 * 2);
    bf16_t* Pemb = (bf16_t*)alloc((size_t)2048 * 1024 * 2);
    bf16_t* kvb  = (bf16_t*)alloc((size_t)8192 * 2048 * 2);
    bf16_t* qub  = (bf16_t*)alloc((size_t)4096 * 1024 * 2);
    bf16_t* qvb  = (bf16_t*)alloc((size_t)4096 * 1024 * 2);
    bf16_t* pb   = (bf16_t*)alloc((size_t)2048 * 1024 * 2);
    bf16_t* awvb = (bf16_t*)alloc((size_t)4096 * 1024 * 2);
    float*  opre = (float*)alloc((size_t)4096 * 1024 * 4);
    float*  Oacc = (float*)alloc((size_t)4096 * 1024 * 4);
    float*  lacc = (float*)alloc((size_t)S_ * B_ * H_ * 4);

    hipMemsetAsync(Oacc, 0, (size_t)4096 * 1024 * 4, stream);
    hipMemsetAsync(lacc, 0, (size_t)S_ * B_ * H_ * 4, stream);

    cvt_all_kernel<<<10240, 256, 0, stream>>>(memory, inputMHA, posEmb, Xbf, Pemb);
    trans_all_kernel<<<dim3(64, 32, 4), dim3(32, 8), 0, stream>>>(
        W_kv, Wkvt, W_q, Wqt, W_p, Wpt, W_o, Wot);

    gemm3_kernel<<<1408, 256, 0, stream>>>(Xbf, Wkvt, kvb, Wqt, qub, qvb, u, v, Pemb, Wpt, pb);

    flash_kernel<<<dim3(56, B_ * H_), 256, 0, stream>>>(qub, qvb, kvb, pb, Oacc, lacc);
    norm_kernel<<<4096, 256, 0, stream>>>(Oacc, lacc, awvb);

    gemmo_kernel<<<256, 256, 0, stream>>>(awvb, Wot, inputMHA, opre);
    ln_kernel<<<S_ * B_, 256, 0, stream>>>(opre, gamma, beta, out);
}

// Round 8
// 421.091 us; speedup vs baseline: 1.6185x; 1.0283x over previous
//
#include <hip/hip_runtime.h>
#include <hip/hip_bf16.h>

#define S_ 1024
#define P_ 1024
#define B_ 4
#define E_ 1024
#define J_ 2048
#define H_ 16
#define I_ 64

typedef __bf16 bf16_t;
typedef __bf16 bf16x8 __attribute__((ext_vector_type(8)));
typedef __bf16 bf16x4 __attribute__((ext_vector_type(4)));
typedef unsigned short u16x8 __attribute__((ext_vector_type(8)));
typedef float f32x4 __attribute__((ext_vector_type(4)));

#define MFMA16(a, b, c) __builtin_amdgcn_mfma_f32_16x16x32_bf16(a, b, c, 0, 0, 0)

// XOR-granule swizzle for stride-64 bf16 LDS tiles (flash + gemm).
#define SWZ(r, c) (((r) << 6) + ((((((c) >> 3)) ^ ((r) & 7)) << 3)) + ((c) & 7))

// async global->LDS 16B/lane; LDS dest is wave-uniform base + lane*16 (linear).
__device__ __forceinline__ void g2l16(const bf16_t* g, bf16_t* l) {
    __builtin_amdgcn_global_load_lds(
        (const __attribute__((address_space(1))) unsigned int*)(const void*)g,
        (__attribute__((address_space(3))) unsigned int*)(void*)l,
        16, 0, 0);
}

// ---------------- fused fp32 -> bf16 converts (memory, inputMHA, posEmb) ----------------
__global__ __launch_bounds__(256) void cvt_all_kernel(const float* __restrict__ memory,
                                                      const float* __restrict__ input,
                                                      const float* __restrict__ posEmb,
                                                      bf16_t* __restrict__ Xbf,
                                                      bf16_t* __restrict__ Pemb) {
    // segments: [0,4096) memory->Xbf, [4096,8192) input->Xbf+P*B*E, [8192,10240) posEmb->Pemb
    int blk = blockIdx.x;
    const float* src;
    bf16_t* dst;
    if (blk < 4096) { src = memory; dst = Xbf; }
    else if (blk < 8192) { blk -= 4096; src = input; dst = Xbf + (size_t)P_ * B_ * E_; }
    else { blk -= 8192; src = posEmb; dst = Pemb; }
    int i = (blk * 256 + threadIdx.x) * 4;
    float4 v = *(const float4*)(src + i);
    bf16x4 o = {(bf16_t)v.x, (bf16_t)v.y, (bf16_t)v.z, (bf16_t)v.w};
    *(bf16x4*)(dst + i) = o;
}

// ---------------- fused weight transposes: W (K x N) fp32 -> W^T (N x K) bf16 ----------------
__global__ void trans_all_kernel(const float* __restrict__ W_kv, bf16_t* __restrict__ Wkvt,
                                 const float* __restrict__ W_q, bf16_t* __restrict__ Wqt,
                                 const float* __restrict__ W_p, bf16_t* __restrict__ Wpt,
                                 const float* __restrict__ W_o, bf16_t* __restrict__ Wot) {
    __shared__ float tile[32][33];
    int z = blockIdx.z;
    const float* W = (z == 0) ? W_kv : (z == 1) ? W_q : (z == 2) ? W_p : W_o;
    bf16_t* Wt = (z == 0) ? Wkvt : (z == 1) ? Wqt : (z == 2) ? Wpt : Wot;
    int N = (z == 0) ? 2048 : 1024;
    if (blockIdx.x * 32 >= N) return;
    int n0 = blockIdx.x * 32, k0 = blockIdx.y * 32;
    int x = threadIdx.x, y = threadIdx.y;
    for (int i = 0; i < 32; i += 8)
        tile[y + i][x] = W[(size_t)(k0 + y + i) * N + n0 + x];
    __syncthreads();
    for (int i = 0; i < 32; i += 8)
        Wt[(size_t)(n0 + y + i) * 1024 + k0 + x] = (bf16_t)tile[x][y + i];  // K == 1024 always
}

// ---------------- bf16 MFMA GEMM tile body (R7: global_load_lds + SWZ LDS) ----------------
__device__ __forceinline__ void gemm_tile(
    const bf16_t* __restrict__ A, const bf16_t* __restrict__ Bt, int N,
    int m0, int n0, int epi,
    bf16_t* __restrict__ out0, bf16_t* __restrict__ out1,
    const float* __restrict__ add0, const float* __restrict__ add1,
    float* __restrict__ outf,
    bf16_t* AlL, bf16_t* BlL) {
    const int K = 1024;
    int tid = threadIdx.x;
    int wave = tid >> 6, lane = tid & 63, quad = lane >> 4, l16 = lane & 15;
    int wm = (wave & 1) * 64, wn = (wave >> 1) * 64;
    int lrow = lane >> 3;                 // row-within-8 this lane stages
    int gsw = ((lane & 7) ^ lrow) << 3;   // pre-swizzled source granule offset (elems)
    f32x4 zero = {0.f, 0.f, 0.f, 0.f};
    f32x4 acc[4][4];
    #pragma unroll
    for (int i = 0; i < 4; i++)
        #pragma unroll
        for (int j = 0; j < 4; j++) acc[i][j] = zero;

    for (int k0 = 0; k0 < K; k0 += 64) {
        __syncthreads();
        #pragma unroll
        for (int r = 0; r < 4; r++) {
            int row0 = r * 32 + wave * 8;     // wave-uniform base row (8 rows/issue)
            g2l16(&A[(size_t)(m0 + row0 + lrow) * K + k0 + gsw], &AlL[row0 * 64]);
            g2l16(&Bt[(size_t)(n0 + row0 + lrow) * K + k0 + gsw], &BlL[row0 * 64]);
        }
        __syncthreads();   // compiler drains vmcnt before this barrier
        #pragma unroll
        for (int ks = 0; ks < 2; ks++) {
            bf16x8 af[4], bfr[4];
            #pragma unroll
            for (int i = 0; i < 4; i++)
                af[i] = *(const bf16x8*)&AlL[SWZ(wm + i * 16 + l16, ks * 32 + quad * 8)];
            #pragma unroll
            for (int j = 0; j < 4; j++)
                bfr[j] = *(const bf16x8*)&BlL[SWZ(wn + j * 16 + l16, ks * 32 + quad * 8)];
            #pragma unroll
            for (int i = 0; i < 4; i++)
                #pragma unroll
                for (int j = 0; j < 4; j++) acc[i][j] = MFMA16(af[i], bfr[j], acc[i][j]);
        }
    }
    #pragma unroll
    for (int i = 0; i < 4; i++)
        #pragma unroll
        for (int j = 0; j < 4; j++)
            #pragma unroll
            for (int reg = 0; reg < 4; reg++) {
                int m = m0 + wm + i * 16 + quad * 4 + reg;
                int n = n0 + wn + j * 16 + l16;
                float v = acc[i][j][reg];
                if (epi == 0) {
                    out0[(size_t)m * N + n] = (bf16_t)v;
                } else if (epi == 1) {
                    out0[(size_t)m * N + n] = (bf16_t)(v + add0[n]);
                    out1[(size_t)m * N + n] = (bf16_t)(v + add1[n]);
                } else {
                    outf[(size_t)m * N + n] = v + add0[(size_t)m * N + n];
                }
            }
}

// ---------------- packed pre-attention GEMMs: kv | q(+u,+v dual) | p ----------------
// grid.x = 1024 + 256 + 128 = 1408 blocks of 128x128.
__global__ __launch_bounds__(256) void gemm3_kernel(
    const bf16_t* __restrict__ Xbf, const bf16_t* __restrict__ Wkvt, bf16_t* __restrict__ kvb,
    const bf16_t* __restrict__ Wqt, bf16_t* __restrict__ qub, bf16_t* __restrict__ qvb,
    const float* __restrict__ u, const float* __restrict__ v,
    const bf16_t* __restrict__ Pemb, const bf16_t* __restrict__ Wpt, bf16_t* __restrict__ pb) {
    __shared__ __attribute__((aligned(16))) bf16_t Al[128 * 64];
    __shared__ __attribute__((aligned(16))) bf16_t Bl[128 * 64];
    int id = blockIdx.x;
    if (id < 1024) {
        gemm_tile(Xbf, Wkvt, 2048, (id >> 4) * 128, (id & 15) * 128, 0,
                  kvb, nullptr, nullptr, nullptr, nullptr, Al, Bl);
    } else if (id < 1280) {
        int t = id - 1024;
        gemm_tile(Xbf + (size_t)P_ * B_ * E_, Wqt, 1024, (t >> 3) * 128, (t & 7) * 128, 1,
                  qub, qvb, u, v, nullptr, Al, Bl);
    } else {
        int t = id - 1280;
        gemm_tile(Pemb, Wpt, 1024, (t >> 3) * 128, (t & 7) * 128, 0,
                  pb, nullptr, nullptr, nullptr, nullptr, Al, Bl);
    }
}

// ---------------- output GEMM: opre = awv @ W_o + inputMHA (fp32) ----------------
__global__ __launch_bounds__(256) void gemmo_kernel(
    const bf16_t* __restrict__ awvb, const bf16_t* __restrict__ Wot,
    const float* __restrict__ inputMHA, float* __restrict__ opre) {
    __shared__ __attribute__((aligned(16))) bf16_t Al[128 * 64];
    __shared__ __attribute__((aligned(16))) bf16_t Bl[128 * 64];
    int id = blockIdx.x;
    gemm_tile(awvb, Wot, 1024, (id >> 3) * 128, (id & 7) * 128, 2,
              nullptr, nullptr, inputMHA, nullptr, opre, Al, Bl);
}

// ---------------- flash attention (R8: T1 XCD-grouped bh decode) ----------------
// Internals identical to the R0-proven + setprio kernel. Only the blockIdx ->
// (chunk x, bh) decode changes: XCD k (linear id & 7, HW round-robin) owns
// bh in [8k, 8k+8), with same-bh chunks temporally adjacent, so each XCD's
// 4MB L2 holds the live K/V panels instead of all 8 XCDs re-fetching all 64.
__global__ __launch_bounds__(256) void flash_kernel(
    const bf16_t* __restrict__ qu, const bf16_t* __restrict__ qv,
    const bf16_t* __restrict__ kv, const bf16_t* __restrict__ pm,
    float* __restrict__ Oacc, float* __restrict__ lacc) {
    __shared__ __attribute__((aligned(16))) bf16_t Klds[64 * 64];
    __shared__ __attribute__((aligned(16))) bf16_t Vt[64 * 64];
    __shared__ __attribute__((aligned(16))) bf16_t Plds[128 * 64];   // ring
    __shared__ __attribute__((aligned(16))) bf16_t Prob[4 * 16 * 64];

    int tid = threadIdx.x;
    int wave = tid >> 6, lane = tid & 63, quad = lane >> 4, l16 = lane & 15;

    // T1 decode: linear -> (xcd, slot); xcd owns 8 consecutive bh.
    int linear = blockIdx.x + 56 * blockIdx.y;   // 0..3583
    int xcd = linear & 7;
    int slot = linear >> 3;                      // 0..447
    int bh = xcd * 8 + slot / 56;                // 8 bh per XCD
    int x = slot % 56;                           // chunk index (same-bh adjacent)

    int s_blk, c;
    if (x < 24) { s_blk = x / 3; c = x - s_blk * 3; }
    else        { int y = x - 24; s_blk = 8 + (y >> 2); c = y & 3; }
    int nt = 17 + s_blk;
    int t0 = c * 8;
    int t1 = t0 + 8; if (t1 > nt) t1 = nt;

    int s0 = s_blk * 64;
    int b = bh >> 4, h = bh & 15;
    int srow0 = s0 + wave * 16;

    const bf16_t* qub = qu + ((size_t)(srow0 + l16) * B_ + b) * 1024 + h * 64 + quad * 8;
    const bf16_t* qvb = qv + ((size_t)(srow0 + l16) * B_ + b) * 1024 + h * 64 + quad * 8;
    bf16x8 aqu0 = *(const bf16x8*)(qub);
    bf16x8 aqu1 = *(const bf16x8*)(qub + 32);
    bf16x8 aqv0 = *(const bf16x8*)(qvb);
    bf16x8 aqv1 = *(const bf16x8*)(qvb + 32);

    f32x4 zero = {0.f, 0.f, 0.f, 0.f};
    f32x4 accO[4];
    #pragma unroll
    for (int ot = 0; ot < 4; ot++) accO[ot] = zero;
    float lrowp[4] = {0.f, 0.f, 0.f, 0.f};

    const int w0u = 960 - s0;
    const int woff = 48 - wave * 16;
    const float SCL = 0.125f * 1.44269504088896f;

    int jr = tid >> 3, seg8g = tid & 7;
    int jp = tid & 31, iseg = tid >> 5;
    uint* VtU = (uint*)&Vt[0];
    bf16_t* ProbW = Prob + (wave << 10);

    {
        int j0 = t0 * 64;
        const bf16_t* kp = kv + ((size_t)(j0 + jr) * B_ + b) * 2048 + h * 64 + seg8g * 8;
        uint4 ka = *(const uint4*)kp;
        uint4 kb = *(const uint4*)(kp + (size_t)32 * B_ * 2048);
        const bf16_t* vp = kv + ((size_t)(j0 + jp * 2) * B_ + b) * 2048 + 1024 + h * 64 + iseg * 8;
        u16x8 va = *(const u16x8*)vp;
        u16x8 vb = *(const u16x8*)(vp + (size_t)B_ * 2048);
        uint4 pd[4];
        #pragma unroll
        for (int r = 0; r < 4; r++) {
            int idx = tid + 256 * r;
            int pr = idx >> 3, pg = idx & 7;
            int lr = w0u + j0 + pr; if (lr > J_ - 1) lr = J_ - 1;
            pd[r] = *(const uint4*)(pm + (size_t)lr * 1024 + h * 64 + pg * 8);
        }
        *(uint4*)&Klds[SWZ(jr, seg8g * 8)] = ka;
        *(uint4*)&Klds[SWZ(jr + 32, seg8g * 8)] = kb;
        #pragma unroll
        for (int e = 0; e < 8; e++) {
            int row = iseg * 8 + e;
            VtU[(row << 5) + ((((jp >> 2) ^ (row & 7)) << 2)) + (jp & 3)] =
                (uint)va[e] | ((uint)vb[e] << 16);
        }
        #pragma unroll
        for (int r = 0; r < 4; r++) {
            int idx = tid + 256 * r;
            int pr = idx >> 3, pg = idx & 7;
            *(uint4*)&Plds[SWZ((w0u + j0 + pr) & 127, pg * 8)] = pd[r];
        }
    }
    __syncthreads();

    for (int it = t0; it < t1; it++) {
        int j0 = it * 64;
        bool pf = (it + 1 < t1);
        uint4 ka, kb, pd0, pd1;
        u16x8 va, vb;
        int pr0 = tid >> 3, pg0 = tid & 7;
        int pr1 = (tid + 256) >> 3, pg1 = tid & 7;
        if (pf) {
            int j1 = j0 + 64;
            const bf16_t* kp = kv + ((size_t)(j1 + jr) * B_ + b) * 2048 + h * 64 + seg8g * 8;
            ka = *(const uint4*)kp;
            kb = *(const uint4*)(kp + (size_t)32 * B_ * 2048);
            const bf16_t* vp = kv + ((size_t)(j1 + jp * 2) * B_ + b) * 2048 + 1024 + h * 64 + iseg * 8;
            va = *(const u16x8*)vp;
            vb = *(const u16x8*)(vp + (size_t)B_ * 2048);
            int lr0 = w0u + j0 + 128 + pr0; if (lr0 > J_ - 1) lr0 = J_ - 1;
            int lr1 = w0u + j0 + 128 + pr1; if (lr1 > J_ - 1) lr1 = J_ - 1;
            pd0 = *(const uint4*)(pm + (size_t)lr0 * 1024 + h * 64 + pg0 * 8);
            pd1 = *(const uint4*)(pm + (size_t)lr1 * 1024 + h * 64 + pg1 * 8);
        }

        f32x4 cs[4];
        #pragma unroll
        for (int t = 0; t < 4; t++) cs[t] = zero;
        __builtin_amdgcn_s_setprio(1);
        #pragma unroll
        for (int ks = 0; ks < 2; ks++) {
            bf16x8 aq = ks ? aqu1 : aqu0;
            #pragma unroll
            for (int t = 0; t < 4; t++) {
                bf16x8 bk = *(const bf16x8*)&Klds[SWZ(t * 16 + l16, ks * 32 + quad * 8)];
                cs[t] = MFMA16(aq, bk, cs[t]);
            }
        }
        f32x4 ep[5];
        #pragma unroll
        for (int t = 0; t < 5; t++) ep[t] = zero;
        #pragma unroll
        for (int ks = 0; ks < 2; ks++) {
            bf16x8 aq = ks ? aqv1 : aqv0;
            #pragma unroll
            for (int t = 0; t < 5; t++) {
                int prow = (w0u + j0 + woff + t * 16 + l16) & 127;
                bf16x8 bp = *(const bf16x8*)&Plds[SWZ(prow, ks * 32 + quad * 8)];
                ep[t] = MFMA16(aq, bp, ep[t]);
            }
        }
        __builtin_amdgcn_s_setprio(0);

        #pragma unroll
        for (int reg = 0; reg < 4; reg++) {
            int r = quad * 4 + reg;
            int s = srow0 + r;
            int idx = l16 + 15 - r;
            int srcl = quad * 16 + (idx & 15);
            float sh[5];
            #pragma unroll
            for (int t = 0; t < 5; t++) sh[t] = __shfl(ep[t][reg], srcl);
            float psum = 0.f;
            #pragma unroll
            for (int t = 0; t < 4; t++) {
                float pos = (idx < 16) ? sh[t] : sh[t + 1];
                float p = exp2f((cs[t][reg] + pos) * SCL);
                p = (j0 + t * 16 + l16 > P_ + s) ? 0.f : p;
                ProbW[SWZ(r, t * 16 + l16)] = (bf16_t)p;
                psum += p;
            }
            lrowp[reg] += psum;
        }

        __builtin_amdgcn_s_setprio(1);
        #pragma unroll
        for (int ks = 0; ks < 2; ks++) {
            bf16x8 pa = *(const bf16x8*)&Prob[(wave << 10) + SWZ(l16, ks * 32 + quad * 8)];
            #pragma unroll
            for (int ot = 0; ot < 4; ot++) {
                bf16x8 bv = *(const bf16x8*)&Vt[SWZ(ot * 16 + l16, ks * 32 + quad * 8)];
                accO[ot] = MFMA16(pa, bv, accO[ot]);
            }
        }
        __builtin_amdgcn_s_setprio(0);

        __syncthreads();
        if (pf) {
            *(uint4*)&Klds[SWZ(jr, seg8g * 8)] = ka;
            *(uint4*)&Klds[SWZ(jr + 32, seg8g * 8)] = kb;
            #pragma unroll
            for (int e2 = 0; e2 < 8; e2++) {
                int row = iseg * 8 + e2;
                VtU[(row << 5) + ((((jp >> 2) ^ (row & 7)) << 2)) + (jp & 3)] =
                    (uint)va[e2] | ((uint)vb[e2] << 16);
            }
            *(uint4*)&Plds[SWZ((w0u + j0 + pr0) & 127, pg0 * 8)] = pd0;
            *(uint4*)&Plds[SWZ((w0u + j0 + pr1) & 127, pg1 * 8)] = pd1;
        }
        __syncthreads();
    }

    #pragma unroll
    for (int reg = 0; reg < 4; reg++) {
        int r = quad * 4 + reg;
        int srow = srow0 + r;
        float l = lrowp[reg];
        #pragma unroll
        for (int d = 1; d < 16; d <<= 1) l += __shfl_xor(l, d);
        if (l16 == 0) atomicAdd(&lacc[((size_t)srow * B_ + b) * H_ + h], l);
        size_t rowoff = ((size_t)srow * B_ + b) * 1024 + h * 64;
        #pragma unroll
        for (int ot = 0; ot < 4; ot++)
            atomicAdd(&Oacc[rowoff + ot * 16 + l16], accO[ot][reg]);
    }
}

// ---------------- combine/normalize: awv = Oacc / lacc ----------------
__global__ __launch_bounds__(256) void norm_kernel(const float* __restrict__ Oacc,
                                                   const float* __restrict__ lacc,
                                                   bf16_t* __restrict__ awv) {
    int i4 = (blockIdx.x * 256 + threadIdx.x) * 4;
    int row = i4 >> 6;
    float inv = 1.0f / lacc[row];
    float4 o = *(const float4*)(Oacc + i4);
    bf16x4 r = {(bf16_t)(o.x * inv), (bf16_t)(o.y * inv),
                (bf16_t)(o.z * inv), (bf16_t)(o.w * inv)};
    *(bf16x4*)(awv + i4) = r;
}

// ---------------- LayerNorm over E=1024 ----------------
__global__ __launch_bounds__(256) void ln_kernel(const float* __restrict__ x,
                                                 const float* __restrict__ gamma,
                                                 const float* __restrict__ beta,
                                                 float* __restrict__ out) {
    int row = blockIdx.x, tid = threadIdx.x;
    int lane = tid & 63, wave = tid >> 6;
    float4 v = ((const float4*)(x + (size_t)row * 1024))[tid];
    float s = v.x + v.y + v.z + v.w;
    float ss = v.x * v.x + v.y * v.y + v.z * v.z + v.w * v.w;
    #pragma unroll
    for (int sh = 1; sh < 64; sh <<= 1) { s += __shfl_xor(s, sh); ss += __shfl_xor(ss, sh); }
    __shared__ float red[8];
    if (lane == 0) { red[wave] = s; red[4 + wave] = ss; }
    __syncthreads();
    s = red[0] + red[1] + red[2] + red[3];
    ss = red[4] + red[5] + red[6] + red[7];
    float mean = s * (1.f / 1024.f);
    float var = ss * (1.f / 1024.f) - mean * mean;
    float inv = rsqrtf(var + 1e-5f);
    float4 g = ((const float4*)gamma)[tid];
    float4 bt = ((const float4*)beta)[tid];
    float4 o;
    o.x = (v.x - mean) * inv * g.x + bt.x;
    o.y = (v.y - mean) * inv * g.y + bt.y;
    o.z = (v.z - mean) * inv * g.z + bt.z;
    o.w = (v.w - mean) * inv * g.w + bt.w;
    ((float4*)(out + (size_t)row * 1024))[tid] = o;
}

extern "C" void kernel_launch(void* const* d_in, const int* in_sizes, int n_in,
                              void* d_out, int out_size, void* d_ws, size_t ws_size,
                              hipStream_t stream) {
    const float* inputMHA = (const float*)d_in[0];
    const float* posEmb   = (const float*)d_in[1];
    const float* memory   = (const float*)d_in[2];
    const float* u        = (const float*)d_in[3];
    const float* v        = (const float*)d_in[4];
    const float* W_kv     = (const float*)d_in[6];
    const float* W_q      = (const float*)d_in[7];
    const float* W_p      = (const float*)d_in[8];
    const float* W_o      = (const float*)d_in[9];
    const float* gamma    = (const float*)d_in[10];
    const float* beta     = (const float*)d_in[11];
    float* out = (float*)d_out;

    char* ws = (char*)d_ws;
    size_t off = 0;
    auto alloc = [&](size_t bytes) -> void* {
        void* p = ws + off;
        off += (bytes + 255) & ~(size_t)255;
        return p;
    };
    bf16_t* Xbf  = (bf16_t*)alloc((size_t)J_ * B_ * E_ * 2);
    bf16_t* Wkvt = (bf16_t*)alloc((size_t)2048 * 1024 * 2);
    bf16_t* Wqt  = (bf16_t*)alloc((size_t)1024 * 1024 * 2);
    bf16_t* Wpt  = (bf16_t*)alloc((size_t)1024 * 1024 * 2);
    bf16_t* Wot  = (bf16_t*)alloc((size_t)1024 * 1024 * 2);
    bf16_t* Pemb = (bf16_t*)alloc((size_t)2048 * 1024 * 2);
    bf16_t* kvb  = (bf16_t*)alloc((size_t)8192 * 2048 * 2);
    bf16_t* qub  = (bf16_t*)alloc((size_t)4096 * 1024 * 2);
    bf16_t* qvb  = (bf16_t*)alloc((size_t)4096 * 1024 * 2);
    bf16_t* pb   = (bf16_t*)alloc((size_t)2048 * 1024 * 2);
    bf16_t* awvb = (bf16_t*)alloc((size_t)4096 * 1024 * 2);
    float*  opre = (float*)alloc((size_t)4096 * 1024 * 4);
    float*  Oacc = (float*)alloc((size_t)4096 * 1024 * 4);
    float*  lacc = (float*)alloc((size_t)S_ * B_ * H_ * 4);

    hipMemsetAsync(Oacc, 0, (size_t)4096 * 1024 * 4, stream);
    hipMemsetAsync(lacc, 0, (size_t)S_ * B_ * H_ * 4, stream);

    cvt_all_kernel<<<10240, 256, 0, stream>>>(memory, inputMHA, posEmb, Xbf, Pemb);
    trans_all_kernel<<<dim3(64, 32, 4), dim3(32, 8), 0, stream>>>(
        W_kv, Wkvt, W_q, Wqt, W_p, Wpt, W_o, Wot);

    gemm3_kernel<<<1408, 256, 0, stream>>>(Xbf, Wkvt, kvb, Wqt, qub, qvb, u, v, Pemb, Wpt, pb);

    flash_kernel<<<dim3(56, B_ * H_), 256, 0, stream>>>(qub, qvb, kvb, pb, Oacc, lacc);
    norm_kernel<<<4096, 256, 0, stream>>>(Oacc, lacc, awvb);

    gemmo_kernel<<<256, 256, 0, stream>>>(awvb, Wot, inputMHA, opre);
    ln_kernel<<<S_ * B_, 256, 0, stream>>>(opre, gamma, beta, out);
}

// Round 9
// 383.355 us; speedup vs baseline: 1.7778x; 1.0984x over previous
//
#include <hip/hip_runtime.h>
#include <hip/hip_bf16.h>

#define S_ 1024
#define P_ 1024
#define B_ 4
#define E_ 1024
#define J_ 2048
#define H_ 16
#define I_ 64

typedef __bf16 bf16_t;
typedef __bf16 bf16x8 __attribute__((ext_vector_type(8)));
typedef __bf16 bf16x4 __attribute__((ext_vector_type(4)));
typedef unsigned short u16x8 __attribute__((ext_vector_type(8)));
typedef float f32x4 __attribute__((ext_vector_type(4)));

#define MFMA16(a, b, c) __builtin_amdgcn_mfma_f32_16x16x32_bf16(a, b, c, 0, 0, 0)

// XOR-granule swizzle for stride-64 bf16 LDS tiles (flash + gemm).
#define SWZ(r, c) (((r) << 6) + ((((((c) >> 3)) ^ ((r) & 7)) << 3)) + ((c) & 7))

// async global->LDS 16B/lane; LDS dest is wave-uniform base + lane*16 (linear).
__device__ __forceinline__ void g2l16(const bf16_t* g, bf16_t* l) {
    __builtin_amdgcn_global_load_lds(
        (const __attribute__((address_space(1))) unsigned int*)(const void*)g,
        (__attribute__((address_space(3))) unsigned int*)(void*)l,
        16, 0, 0);
}

// ---------------- fused fp32 -> bf16 converts (memory, inputMHA, posEmb) ----------------
__global__ __launch_bounds__(256) void cvt_all_kernel(const float* __restrict__ memory,
                                                      const float* __restrict__ input,
                                                      const float* __restrict__ posEmb,
                                                      bf16_t* __restrict__ Xbf,
                                                      bf16_t* __restrict__ Pemb) {
    // segments: [0,4096) memory->Xbf, [4096,8192) input->Xbf+P*B*E, [8192,10240) posEmb->Pemb
    int blk = blockIdx.x;
    const float* src;
    bf16_t* dst;
    if (blk < 4096) { src = memory; dst = Xbf; }
    else if (blk < 8192) { blk -= 4096; src = input; dst = Xbf + (size_t)P_ * B_ * E_; }
    else { blk -= 8192; src = posEmb; dst = Pemb; }
    int i = (blk * 256 + threadIdx.x) * 4;
    float4 v = *(const float4*)(src + i);
    bf16x4 o = {(bf16_t)v.x, (bf16_t)v.y, (bf16_t)v.z, (bf16_t)v.w};
    *(bf16x4*)(dst + i) = o;
}

// ---------------- fused weight transposes: W (K x N) fp32 -> W^T (N x K) bf16 ----------------
__global__ void trans_all_kernel(const float* __restrict__ W_kv, bf16_t* __restrict__ Wkvt,
                                 const float* __restrict__ W_q, bf16_t* __restrict__ Wqt,
                                 const float* __restrict__ W_p, bf16_t* __restrict__ Wpt,
                                 const float* __restrict__ W_o, bf16_t* __restrict__ Wot) {
    __shared__ float tile[32][33];
    int z = blockIdx.z;
    const float* W = (z == 0) ? W_kv : (z == 1) ? W_q : (z == 2) ? W_p : W_o;
    bf16_t* Wt = (z == 0) ? Wkvt : (z == 1) ? Wqt : (z == 2) ? Wpt : Wot;
    int N = (z == 0) ? 2048 : 1024;
    if (blockIdx.x * 32 >= N) return;
    int n0 = blockIdx.x * 32, k0 = blockIdx.y * 32;
    int x = threadIdx.x, y = threadIdx.y;
    for (int i = 0; i < 32; i += 8)
        tile[y + i][x] = W[(size_t)(k0 + y + i) * N + n0 + x];
    __syncthreads();
    for (int i = 0; i < 32; i += 8)
        Wt[(size_t)(n0 + y + i) * 1024 + k0 + x] = (bf16_t)tile[x][y + i];  // K == 1024 always
}

// ---------------- bf16 MFMA GEMM tile body (R7: global_load_lds + SWZ LDS) ----------------
__device__ __forceinline__ void gemm_tile(
    const bf16_t* __restrict__ A, const bf16_t* __restrict__ Bt, int N,
    int m0, int n0, int epi,
    bf16_t* __restrict__ out0, bf16_t* __restrict__ out1,
    const float* __restrict__ add0, const float* __restrict__ add1,
    float* __restrict__ outf,
    bf16_t* AlL, bf16_t* BlL) {
    const int K = 1024;
    int tid = threadIdx.x;
    int wave = tid >> 6, lane = tid & 63, quad = lane >> 4, l16 = lane & 15;
    int wm = (wave & 1) * 64, wn = (wave >> 1) * 64;
    int lrow = lane >> 3;                 // row-within-8 this lane stages
    int gsw = ((lane & 7) ^ lrow) << 3;   // pre-swizzled source granule offset (elems)
    f32x4 zero = {0.f, 0.f, 0.f, 0.f};
    f32x4 acc[4][4];
    #pragma unroll
    for (int i = 0; i < 4; i++)
        #pragma unroll
        for (int j = 0; j < 4; j++) acc[i][j] = zero;

    for (int k0 = 0; k0 < K; k0 += 64) {
        __syncthreads();
        #pragma unroll
        for (int r = 0; r < 4; r++) {
            int row0 = r * 32 + wave * 8;     // wave-uniform base row (8 rows/issue)
            g2l16(&A[(size_t)(m0 + row0 + lrow) * K + k0 + gsw], &AlL[row0 * 64]);
            g2l16(&Bt[(size_t)(n0 + row0 + lrow) * K + k0 + gsw], &BlL[row0 * 64]);
        }
        __syncthreads();   // compiler drains vmcnt before this barrier
        #pragma unroll
        for (int ks = 0; ks < 2; ks++) {
            bf16x8 af[4], bfr[4];
            #pragma unroll
            for (int i = 0; i < 4; i++)
                af[i] = *(const bf16x8*)&AlL[SWZ(wm + i * 16 + l16, ks * 32 + quad * 8)];
            #pragma unroll
            for (int j = 0; j < 4; j++)
                bfr[j] = *(const bf16x8*)&BlL[SWZ(wn + j * 16 + l16, ks * 32 + quad * 8)];
            #pragma unroll
            for (int i = 0; i < 4; i++)
                #pragma unroll
                for (int j = 0; j < 4; j++) acc[i][j] = MFMA16(af[i], bfr[j], acc[i][j]);
        }
    }
    #pragma unroll
    for (int i = 0; i < 4; i++)
        #pragma unroll
        for (int j = 0; j < 4; j++)
            #pragma unroll
            for (int reg = 0; reg < 4; reg++) {
                int m = m0 + wm + i * 16 + quad * 4 + reg;
                int n = n0 + wn + j * 16 + l16;
                float v = acc[i][j][reg];
                if (epi == 0) {
                    out0[(size_t)m * N + n] = (bf16_t)v;
                } else if (epi == 1) {
                    out0[(size_t)m * N + n] = (bf16_t)(v + add0[n]);
                    out1[(size_t)m * N + n] = (bf16_t)(v + add1[n]);
                } else {
                    outf[(size_t)m * N + n] = v + add0[(size_t)m * N + n];
                }
            }
}

// ---------------- packed pre-attention GEMMs: kv | q(+u,+v dual) | p ----------------
// grid.x = 1024 + 256 + 128 = 1408 blocks of 128x128.
__global__ __launch_bounds__(256) void gemm3_kernel(
    const bf16_t* __restrict__ Xbf, const bf16_t* __restrict__ Wkvt, bf16_t* __restrict__ kvb,
    const bf16_t* __restrict__ Wqt, bf16_t* __restrict__ qub, bf16_t* __restrict__ qvb,
    const float* __restrict__ u, const float* __restrict__ v,
    const bf16_t* __restrict__ Pemb, const bf16_t* __restrict__ Wpt, bf16_t* __restrict__ pb) {
    __shared__ __attribute__((aligned(16))) bf16_t Al[128 * 64];
    __shared__ __attribute__((aligned(16))) bf16_t Bl[128 * 64];
    int id = blockIdx.x;
    if (id < 1024) {
        gemm_tile(Xbf, Wkvt, 2048, (id >> 4) * 128, (id & 15) * 128, 0,
                  kvb, nullptr, nullptr, nullptr, nullptr, Al, Bl);
    } else if (id < 1280) {
        int t = id - 1024;
        gemm_tile(Xbf + (size_t)P_ * B_ * E_, Wqt, 1024, (t >> 3) * 128, (t & 7) * 128, 1,
                  qub, qvb, u, v, nullptr, Al, Bl);
    } else {
        int t = id - 1280;
        gemm_tile(Pemb, Wpt, 1024, (t >> 3) * 128, (t & 7) * 128, 0,
                  pb, nullptr, nullptr, nullptr, nullptr, Al, Bl);
    }
}

// ---------------- output GEMM: opre = awv @ W_o + inputMHA (fp32) ----------------
__global__ __launch_bounds__(256) void gemmo_kernel(
    const bf16_t* __restrict__ awvb, const bf16_t* __restrict__ Wot,
    const float* __restrict__ inputMHA, float* __restrict__ opre) {
    __shared__ __attribute__((aligned(16))) bf16_t Al[128 * 64];
    __shared__ __attribute__((aligned(16))) bf16_t Bl[128 * 64];
    int id = blockIdx.x;
    gemm_tile(awvb, Wot, 1024, (id >> 3) * 128, (id & 7) * 128, 2,
              nullptr, nullptr, inputMHA, nullptr, opre, Al, Bl);
}

// ---------------- flash attention (R9: ownership + fused normalize) ----------------
// One block owns one (s_blk, bh) tile end-to-end: runs all nt = 17+s_blk j-tiles,
// then divides by the complete row-sum and stores awv bf16 directly. No Oacc/lacc
// atomics, no memset, no norm kernel. Grid = 1024 = 256 CUs x 4 blocks (LDS-capacity
// residency). Decode keeps T1 XCD-grouping (8 bh/XCD) and balances each CU's 4
// blocks to exactly 98 iterations ({a, a+4, 15-a, 11-a} s_blk quadruples).
__global__ __launch_bounds__(256) void flash_kernel(
    const bf16_t* __restrict__ qu, const bf16_t* __restrict__ qv,
    const bf16_t* __restrict__ kv, const bf16_t* __restrict__ pm,
    bf16_t* __restrict__ awv) {
    __shared__ __attribute__((aligned(16))) bf16_t Klds[64 * 64];
    __shared__ __attribute__((aligned(16))) bf16_t Vt[64 * 64];
    __shared__ __attribute__((aligned(16))) bf16_t Plds[128 * 64];   // ring
    __shared__ __attribute__((aligned(16))) bf16_t Prob[4 * 16 * 64];

    int tid = threadIdx.x;
    int wave = tid >> 6, lane = tid & 63, quad = lane >> 4, l16 = lane & 15;

    // decode: XCD k owns bh in [8k,8k+8); per-CU s_blk quadruple sums to 30.
    int linear = blockIdx.x;                 // 0..1023
    int xcd = linear & 7;
    int p = linear >> 3;                     // 0..127 within XCD
    int bh = xcd * 8 + ((p >> 2) & 7);
    int q4 = ((p >> 5) << 2) | (p & 3);      // 0..15
    int s_blk = (q4 < 8) ? q4 : 23 - q4;
    int nt = 17 + s_blk;
    int t0 = 0;
    int t1 = nt;

    int s0 = s_blk * 64;
    int b = bh >> 4, h = bh & 15;
    int srow0 = s0 + wave * 16;

    const bf16_t* qub = qu + ((size_t)(srow0 + l16) * B_ + b) * 1024 + h * 64 + quad * 8;
    const bf16_t* qvb = qv + ((size_t)(srow0 + l16) * B_ + b) * 1024 + h * 64 + quad * 8;
    bf16x8 aqu0 = *(const bf16x8*)(qub);
    bf16x8 aqu1 = *(const bf16x8*)(qub + 32);
    bf16x8 aqv0 = *(const bf16x8*)(qvb);
    bf16x8 aqv1 = *(const bf16x8*)(qvb + 32);

    f32x4 zero = {0.f, 0.f, 0.f, 0.f};
    f32x4 accO[4];
    #pragma unroll
    for (int ot = 0; ot < 4; ot++) accO[ot] = zero;
    float lrowp[4] = {0.f, 0.f, 0.f, 0.f};

    const int w0u = 960 - s0;
    const int woff = 48 - wave * 16;
    const float SCL = 0.125f * 1.44269504088896f;

    int jr = tid >> 3, seg8g = tid & 7;
    int jp = tid & 31, iseg = tid >> 5;
    uint* VtU = (uint*)&Vt[0];
    bf16_t* ProbW = Prob + (wave << 10);

    {
        int j0 = t0 * 64;
        const bf16_t* kp = kv + ((size_t)(j0 + jr) * B_ + b) * 2048 + h * 64 + seg8g * 8;
        uint4 ka = *(const uint4*)kp;
        uint4 kb = *(const uint4*)(kp + (size_t)32 * B_ * 2048);
        const bf16_t* vp = kv + ((size_t)(j0 + jp * 2) * B_ + b) * 2048 + 1024 + h * 64 + iseg * 8;
        u16x8 va = *(const u16x8*)vp;
        u16x8 vb = *(const u16x8*)(vp + (size_t)B_ * 2048);
        uint4 pd[4];
        #pragma unroll
        for (int r = 0; r < 4; r++) {
            int idx = tid + 256 * r;
            int pr = idx >> 3, pg = idx & 7;
            int lr = w0u + j0 + pr; if (lr > J_ - 1) lr = J_ - 1;
            pd[r] = *(const uint4*)(pm + (size_t)lr * 1024 + h * 64 + pg * 8);
        }
        *(uint4*)&Klds[SWZ(jr, seg8g * 8)] = ka;
        *(uint4*)&Klds[SWZ(jr + 32, seg8g * 8)] = kb;
        #pragma unroll
        for (int e = 0; e < 8; e++) {
            int row = iseg * 8 + e;
            VtU[(row << 5) + ((((jp >> 2) ^ (row & 7)) << 2)) + (jp & 3)] =
                (uint)va[e] | ((uint)vb[e] << 16);
        }
        #pragma unroll
        for (int r = 0; r < 4; r++) {
            int idx = tid + 256 * r;
            int pr = idx >> 3, pg = idx & 7;
            *(uint4*)&Plds[SWZ((w0u + j0 + pr) & 127, pg * 8)] = pd[r];
        }
    }
    __syncthreads();

    for (int it = t0; it < t1; it++) {
        int j0 = it * 64;
        bool pf = (it + 1 < t1);
        uint4 ka, kb, pd0, pd1;
        u16x8 va, vb;
        int pr0 = tid >> 3, pg0 = tid & 7;
        int pr1 = (tid + 256) >> 3, pg1 = tid & 7;
        if (pf) {
            int j1 = j0 + 64;
            const bf16_t* kp = kv + ((size_t)(j1 + jr) * B_ + b) * 2048 + h * 64 + seg8g * 8;
            ka = *(const uint4*)kp;
            kb = *(const uint4*)(kp + (size_t)32 * B_ * 2048);
            const bf16_t* vp = kv + ((size_t)(j1 + jp * 2) * B_ + b) * 2048 + 1024 + h * 64 + iseg * 8;
            va = *(const u16x8*)vp;
            vb = *(const u16x8*)(vp + (size_t)B_ * 2048);
            int lr0 = w0u + j0 + 128 + pr0; if (lr0 > J_ - 1) lr0 = J_ - 1;
            int lr1 = w0u + j0 + 128 + pr1; if (lr1 > J_ - 1) lr1 = J_ - 1;
            pd0 = *(const uint4*)(pm + (size_t)lr0 * 1024 + h * 64 + pg0 * 8);
            pd1 = *(const uint4*)(pm + (size_t)lr1 * 1024 + h * 64 + pg1 * 8);
        }

        f32x4 cs[4];
        #pragma unroll
        for (int t = 0; t < 4; t++) cs[t] = zero;
        __builtin_amdgcn_s_setprio(1);
        #pragma unroll
        for (int ks = 0; ks < 2; ks++) {
            bf16x8 aq = ks ? aqu1 : aqu0;
            #pragma unroll
            for (int t = 0; t < 4; t++) {
                bf16x8 bk = *(const bf16x8*)&Klds[SWZ(t * 16 + l16, ks * 32 + quad * 8)];
                cs[t] = MFMA16(aq, bk, cs[t]);
            }
        }
        f32x4 ep[5];
        #pragma unroll
        for (int t = 0; t < 5; t++) ep[t] = zero;
        #pragma unroll
        for (int ks = 0; ks < 2; ks++) {
            bf16x8 aq = ks ? aqv1 : aqv0;
            #pragma unroll
            for (int t = 0; t < 5; t++) {
                int prow = (w0u + j0 + woff + t * 16 + l16) & 127;
                bf16x8 bp = *(const bf16x8*)&Plds[SWZ(prow, ks * 32 + quad * 8)];
                ep[t] = MFMA16(aq, bp, ep[t]);
            }
        }
        __builtin_amdgcn_s_setprio(0);

        #pragma unroll
        for (int reg = 0; reg < 4; reg++) {
            int r = quad * 4 + reg;
            int s = srow0 + r;
            int idx = l16 + 15 - r;
            int srcl = quad * 16 + (idx & 15);
            float sh[5];
            #pragma unroll
            for (int t = 0; t < 5; t++) sh[t] = __shfl(ep[t][reg], srcl);
            float psum = 0.f;
            #pragma unroll
            for (int t = 0; t < 4; t++) {
                float pos = (idx < 16) ? sh[t] : sh[t + 1];
                float p2 = exp2f((cs[t][reg] + pos) * SCL);
                p2 = (j0 + t * 16 + l16 > P_ + s) ? 0.f : p2;
                ProbW[SWZ(r, t * 16 + l16)] = (bf16_t)p2;
                psum += p2;
            }
            lrowp[reg] += psum;
        }

        __builtin_amdgcn_s_setprio(1);
        #pragma unroll
        for (int ks = 0; ks < 2; ks++) {
            bf16x8 pa = *(const bf16x8*)&Prob[(wave << 10) + SWZ(l16, ks * 32 + quad * 8)];
            #pragma unroll
            for (int ot = 0; ot < 4; ot++) {
                bf16x8 bv = *(const bf16x8*)&Vt[SWZ(ot * 16 + l16, ks * 32 + quad * 8)];
                accO[ot] = MFMA16(pa, bv, accO[ot]);
            }
        }
        __builtin_amdgcn_s_setprio(0);

        __syncthreads();
        if (pf) {
            *(uint4*)&Klds[SWZ(jr, seg8g * 8)] = ka;
            *(uint4*)&Klds[SWZ(jr + 32, seg8g * 8)] = kb;
            #pragma unroll
            for (int e2 = 0; e2 < 8; e2++) {
                int row = iseg * 8 + e2;
                VtU[(row << 5) + ((((jp >> 2) ^ (row & 7)) << 2)) + (jp & 3)] =
                    (uint)va[e2] | ((uint)vb[e2] << 16);
            }
            *(uint4*)&Plds[SWZ((w0u + j0 + pr0) & 127, pg0 * 8)] = pd0;
            *(uint4*)&Plds[SWZ((w0u + j0 + pr1) & 127, pg1 * 8)] = pd1;
        }
        __syncthreads();
    }

    // fused normalize + direct bf16 store (row-sum is complete: block owns the row)
    #pragma unroll
    for (int reg = 0; reg < 4; reg++) {
        int r = quad * 4 + reg;
        int srow = srow0 + r;
        float l = lrowp[reg];
        #pragma unroll
        for (int d = 1; d < 16; d <<= 1) l += __shfl_xor(l, d);
        float inv = 1.0f / l;
        size_t rowoff = ((size_t)srow * B_ + b) * 1024 + h * 64;
        #pragma unroll
        for (int ot = 0; ot < 4; ot++)
            awv[rowoff + ot * 16 + l16] = (bf16_t)(accO[ot][reg] * inv);
    }
}

// ---------------- LayerNorm over E=1024 ----------------
__global__ __launch_bounds__(256) void ln_kernel(const float* __restrict__ x,
                                                 const float* __restrict__ gamma,
                                                 const float* __restrict__ beta,
                                                 float* __restrict__ out) {
    int row = blockIdx.x, tid = threadIdx.x;
    int lane = tid & 63, wave = tid >> 6;
    float4 v = ((const float4*)(x + (size_t)row * 1024))[tid];
    float s = v.x + v.y + v.z + v.w;
    float ss = v.x * v.x + v.y * v.y + v.z * v.z + v.w * v.w;
    #pragma unroll
    for (int sh = 1; sh < 64; sh <<= 1) { s += __shfl_xor(s, sh); ss += __shfl_xor(ss, sh); }
    __shared__ float red[8];
    if (lane == 0) { red[wave] = s; red[4 + wave] = ss; }
    __syncthreads();
    s = red[0] + red[1] + red[2] + red[3];
    ss = red[4] + red[5] + red[6] + red[7];
    float mean = s * (1.f / 1024.f);
    float var = ss * (1.f / 1024.f) - mean * mean;
    float inv = rsqrtf(var + 1e-5f);
    float4 g = ((const float4*)gamma)[tid];
    float4 bt = ((const float4*)beta)[tid];
    float4 o;
    o.x = (v.x - mean) * inv * g.x + bt.x;
    o.y = (v.y - mean) * inv * g.y + bt.y;
    o.z = (v.z - mean) * inv * g.z + bt.z;
    o.w = (v.w - mean) * inv * g.w + bt.w;
    ((float4*)(out + (size_t)row * 1024))[tid] = o;
}

extern "C" void kernel_launch(void* const* d_in, const int* in_sizes, int n_in,
                              void* d_out, int out_size, void* d_ws, size_t ws_size,
                              hipStream_t stream) {
    const float* inputMHA = (const float*)d_in[0];
    const float* posEmb   = (const float*)d_in[1];
    const float* memory   = (const float*)d_in[2];
    const float* u        = (const float*)d_in[3];
    const float* v        = (const float*)d_in[4];
    const float* W_kv     = (const float*)d_in[6];
    const float* W_q      = (const float*)d_in[7];
    const float* W_p      = (const float*)d_in[8];
    const float* W_o      = (const float*)d_in[9];
    const float* gamma    = (const float*)d_in[10];
    const float* beta     = (const float*)d_in[11];
    float* out = (float*)d_out;

    char* ws = (char*)d_ws;
    size_t off = 0;
    auto alloc = [&](size_t bytes) -> void* {
        void* p = ws + off;
        off += (bytes + 255) & ~(size_t)255;
        return p;
    };
    bf16_t* Xbf  = (bf16_t*)alloc((size_t)J_ * B_ * E_ * 2);
    bf16_t* Wkvt = (bf16_t*)alloc((size_t)2048 * 1024 * 2);
    bf16_t* Wqt  = (bf16_t*)alloc((size_t)1024 * 1024 * 2);
    bf16_t* Wpt  = (bf16_t*)alloc((size_t)1024 * 1024 * 2);
    bf16_t* Wot  = (bf16_t*)alloc((size_t)1024 * 1024 * 2);
    bf16_t* Pemb = (bf16_t*)alloc((size_t)2048 * 1024 * 2);
    bf16_t* kvb  = (bf16_t*)alloc((size_t)8192 * 2048 * 2);
    bf16_t* qub  = (bf16_t*)alloc((size_t)4096 * 1024 * 2);
    bf16_t* qvb  = (bf16_t*)alloc((size_t)4096 * 1024 * 2);
    bf16_t* pb   = (bf16_t*)alloc((size_t)2048 * 1024 * 2);
    bf16_t* awvb = (bf16_t*)alloc((size_t)4096 * 1024 * 2);
    float*  opre = (float*)alloc((size_t)4096 * 1024 * 4);

    cvt_all_kernel<<<10240, 256, 0, stream>>>(memory, inputMHA, posEmb, Xbf, Pemb);
    trans_all_kernel<<<dim3(64, 32, 4), dim3(32, 8), 0, stream>>>(
        W_kv, Wkvt, W_q, Wqt, W_p, Wpt, W_o, Wot);

    gemm3_kernel<<<1408, 256, 0, stream>>>(Xbf, Wkvt, kvb, Wqt, qub, qvb, u, v, Pemb, Wpt, pb);

    flash_kernel<<<1024, 256, 0, stream>>>(qub, qvb, kvb, pb, awvb);

    gemmo_kernel<<<256, 256, 0, stream>>>(awvb, Wot, inputMHA, opre);
    ln_kernel<<<S_ * B_, 256, 0, stream>>>(opre, gamma, beta, out);
}

// Round 10
// 378.543 us; speedup vs baseline: 1.8004x; 1.0127x over previous
//
#include <hip/hip_runtime.h>
#include <hip/hip_bf16.h>

#define S_ 1024
#define P_ 1024
#define B_ 4
#define E_ 1024
#define J_ 2048
#define H_ 16
#define I_ 64

typedef __bf16 bf16_t;
typedef __bf16 bf16x8 __attribute__((ext_vector_type(8)));
typedef __bf16 bf16x4 __attribute__((ext_vector_type(4)));
typedef unsigned short u16x8 __attribute__((ext_vector_type(8)));
typedef float f32x4 __attribute__((ext_vector_type(4)));

#define MFMA16(a, b, c) __builtin_amdgcn_mfma_f32_16x16x32_bf16(a, b, c, 0, 0, 0)

// XOR-granule swizzle for stride-64 bf16 LDS tiles (flash + gemm).
#define SWZ(r, c) (((r) << 6) + ((((((c) >> 3)) ^ ((r) & 7)) << 3)) + ((c) & 7))

// async global->LDS 16B/lane; LDS dest is wave-uniform base + lane*16 (linear).
__device__ __forceinline__ void g2l16(const bf16_t* g, bf16_t* l) {
    __builtin_amdgcn_global_load_lds(
        (const __attribute__((address_space(1))) unsigned int*)(const void*)g,
        (__attribute__((address_space(3))) unsigned int*)(void*)l,
        16, 0, 0);
}

// ---------------- fused fp32 -> bf16 converts (memory, inputMHA, posEmb) ----------------
__global__ __launch_bounds__(256) void cvt_all_kernel(const float* __restrict__ memory,
                                                      const float* __restrict__ input,
                                                      const float* __restrict__ posEmb,
                                                      bf16_t* __restrict__ Xbf,
                                                      bf16_t* __restrict__ Pemb) {
    // segments: [0,4096) memory->Xbf, [4096,8192) input->Xbf+P*B*E, [8192,10240) posEmb->Pemb
    int blk = blockIdx.x;
    const float* src;
    bf16_t* dst;
    if (blk < 4096) { src = memory; dst = Xbf; }
    else if (blk < 8192) { blk -= 4096; src = input; dst = Xbf + (size_t)P_ * B_ * E_; }
    else { blk -= 8192; src = posEmb; dst = Pemb; }
    int i = (blk * 256 + threadIdx.x) * 4;
    float4 v = *(const float4*)(src + i);
    bf16x4 o = {(bf16_t)v.x, (bf16_t)v.y, (bf16_t)v.z, (bf16_t)v.w};
    *(bf16x4*)(dst + i) = o;
}

// ---------------- fused weight transposes: W (K x N) fp32 -> W^T (N x K) bf16 ----------------
__global__ void trans_all_kernel(const float* __restrict__ W_kv, bf16_t* __restrict__ Wkvt,
                                 const float* __restrict__ W_q, bf16_t* __restrict__ Wqt,
                                 const float* __restrict__ W_p, bf16_t* __restrict__ Wpt,
                                 const float* __restrict__ W_o, bf16_t* __restrict__ Wot) {
    __shared__ float tile[32][33];
    int z = blockIdx.z;
    const float* W = (z == 0) ? W_kv : (z == 1) ? W_q : (z == 2) ? W_p : W_o;
    bf16_t* Wt = (z == 0) ? Wkvt : (z == 1) ? Wqt : (z == 2) ? Wpt : Wot;
    int N = (z == 0) ? 2048 : 1024;
    if (blockIdx.x * 32 >= N) return;
    int n0 = blockIdx.x * 32, k0 = blockIdx.y * 32;
    int x = threadIdx.x, y = threadIdx.y;
    for (int i = 0; i < 32; i += 8)
        tile[y + i][x] = W[(size_t)(k0 + y + i) * N + n0 + x];
    __syncthreads();
    for (int i = 0; i < 32; i += 8)
        Wt[(size_t)(n0 + y + i) * 1024 + k0 + x] = (bf16_t)tile[x][y + i];  // K == 1024 always
}

// ---------------- bf16 MFMA GEMM tile body (R7: global_load_lds + SWZ LDS) ----------------
__device__ __forceinline__ void gemm_tile(
    const bf16_t* __restrict__ A, const bf16_t* __restrict__ Bt, int N,
    int m0, int n0, int epi,
    bf16_t* __restrict__ out0, bf16_t* __restrict__ out1,
    const float* __restrict__ add0, const float* __restrict__ add1,
    float* __restrict__ outf,
    bf16_t* AlL, bf16_t* BlL) {
    const int K = 1024;
    int tid = threadIdx.x;
    int wave = tid >> 6, lane = tid & 63, quad = lane >> 4, l16 = lane & 15;
    int wm = (wave & 1) * 64, wn = (wave >> 1) * 64;
    int lrow = lane >> 3;                 // row-within-8 this lane stages
    int gsw = ((lane & 7) ^ lrow) << 3;   // pre-swizzled source granule offset (elems)
    f32x4 zero = {0.f, 0.f, 0.f, 0.f};
    f32x4 acc[4][4];
    #pragma unroll
    for (int i = 0; i < 4; i++)
        #pragma unroll
        for (int j = 0; j < 4; j++) acc[i][j] = zero;

    for (int k0 = 0; k0 < K; k0 += 64) {
        __syncthreads();
        #pragma unroll
        for (int r = 0; r < 4; r++) {
            int row0 = r * 32 + wave * 8;     // wave-uniform base row (8 rows/issue)
            g2l16(&A[(size_t)(m0 + row0 + lrow) * K + k0 + gsw], &AlL[row0 * 64]);
            g2l16(&Bt[(size_t)(n0 + row0 + lrow) * K + k0 + gsw], &BlL[row0 * 64]);
        }
        __syncthreads();   // compiler drains vmcnt before this barrier
        #pragma unroll
        for (int ks = 0; ks < 2; ks++) {
            bf16x8 af[4], bfr[4];
            #pragma unroll
            for (int i = 0; i < 4; i++)
                af[i] = *(const bf16x8*)&AlL[SWZ(wm + i * 16 + l16, ks * 32 + quad * 8)];
            #pragma unroll
            for (int j = 0; j < 4; j++)
                bfr[j] = *(const bf16x8*)&BlL[SWZ(wn + j * 16 + l16, ks * 32 + quad * 8)];
            #pragma unroll
            for (int i = 0; i < 4; i++)
                #pragma unroll
                for (int j = 0; j < 4; j++) acc[i][j] = MFMA16(af[i], bfr[j], acc[i][j]);
        }
    }
    #pragma unroll
    for (int i = 0; i < 4; i++)
        #pragma unroll
        for (int j = 0; j < 4; j++)
            #pragma unroll
            for (int reg = 0; reg < 4; reg++) {
                int m = m0 + wm + i * 16 + quad * 4 + reg;
                int n = n0 + wn + j * 16 + l16;
                float v = acc[i][j][reg];
                if (epi == 0) {
                    out0[(size_t)m * N + n] = (bf16_t)v;
                } else if (epi == 1) {
                    out0[(size_t)m * N + n] = (bf16_t)(v + add0[n]);
                    out1[(size_t)m * N + n] = (bf16_t)(v + add1[n]);
                } else {
                    outf[(size_t)m * N + n] = v + add0[(size_t)m * N + n];
                }
            }
}

// ---------------- packed pre-attention GEMMs: kv | q(+u,+v dual) | p ----------------
// grid.x = 1024 + 256 + 128 = 1408 blocks of 128x128.
// R10: T1 XCD-grouped tile decode per segment (segment bases are =0 mod 8, so
// t&7 matches the HW linear-id round-robin). Each XCD owns a contiguous M-slab
// and sweeps all N-cols: per-XCD working set (A-slab + full B) fits the 4MB L2,
// eliminating cross-XCD panel re-fetch (same mechanism as flash's R8 fix).
__global__ __launch_bounds__(256) void gemm3_kernel(
    const bf16_t* __restrict__ Xbf, const bf16_t* __restrict__ Wkvt, bf16_t* __restrict__ kvb,
    const bf16_t* __restrict__ Wqt, bf16_t* __restrict__ qub, bf16_t* __restrict__ qvb,
    const float* __restrict__ u, const float* __restrict__ v,
    const bf16_t* __restrict__ Pemb, const bf16_t* __restrict__ Wpt, bf16_t* __restrict__ pb) {
    __shared__ __attribute__((aligned(16))) bf16_t Al[128 * 64];
    __shared__ __attribute__((aligned(16))) bf16_t Bl[128 * 64];
    int id = blockIdx.x;
    if (id < 1024) {
        // kv: 64 M x 16 N tiles; XCD owns 8 M-rows (A-slab 2MB) x all 16 N.
        int xcd = id & 7, s = id >> 3;
        int m = xcd * 8 + (s & 7), n = s >> 3;
        gemm_tile(Xbf, Wkvt, 2048, m * 128, n * 128, 0,
                  kvb, nullptr, nullptr, nullptr, nullptr, Al, Bl);
    } else if (id < 1280) {
        // q: 32 M x 8 N tiles; XCD owns 4 M-rows x all 8 N.
        int t = id - 1024;
        int xcd = t & 7, s = t >> 3;
        int m = xcd * 4 + (s & 3), n = s >> 2;
        gemm_tile(Xbf + (size_t)P_ * B_ * E_, Wqt, 1024, m * 128, n * 128, 1,
                  qub, qvb, u, v, nullptr, Al, Bl);
    } else {
        // p: 16 M x 8 N tiles; XCD owns 2 M-rows x all 8 N.
        int t = id - 1280;
        int xcd = t & 7, s = t >> 3;
        int m = xcd * 2 + (s & 1), n = s >> 1;
        gemm_tile(Pemb, Wpt, 1024, m * 128, n * 128, 0,
                  pb, nullptr, nullptr, nullptr, nullptr, Al, Bl);
    }
}

// ---------------- output GEMM: opre = awv @ W_o + inputMHA (fp32) ----------------
// R10: same T1 decode (32 M x 8 N; XCD owns 4 M-rows x all 8 N).
__global__ __launch_bounds__(256) void gemmo_kernel(
    const bf16_t* __restrict__ awvb, const bf16_t* __restrict__ Wot,
    const float* __restrict__ inputMHA, float* __restrict__ opre) {
    __shared__ __attribute__((aligned(16))) bf16_t Al[128 * 64];
    __shared__ __attribute__((aligned(16))) bf16_t Bl[128 * 64];
    int id = blockIdx.x;
    int xcd = id & 7, s = id >> 3;
    int m = xcd * 4 + (s & 3), n = s >> 2;
    gemm_tile(awvb, Wot, 1024, m * 128, n * 128, 2,
              nullptr, nullptr, inputMHA, nullptr, opre, Al, Bl);
}

// ---------------- flash attention (R9: ownership + fused normalize) ----------------
// One block owns one (s_blk, bh) tile end-to-end: runs all nt = 17+s_blk j-tiles,
// then divides by the complete row-sum and stores awv bf16 directly. No Oacc/lacc
// atomics, no memset, no norm kernel. Grid = 1024 = 256 CUs x 4 blocks (LDS-capacity
// residency). Decode keeps T1 XCD-grouping (8 bh/XCD) and balances each CU's 4
// blocks to exactly 98 iterations ({a, a+4, 15-a, 11-a} s_blk quadruples).
__global__ __launch_bounds__(256) void flash_kernel(
    const bf16_t* __restrict__ qu, const bf16_t* __restrict__ qv,
    const bf16_t* __restrict__ kv, const bf16_t* __restrict__ pm,
    bf16_t* __restrict__ awv) {
    __shared__ __attribute__((aligned(16))) bf16_t Klds[64 * 64];
    __shared__ __attribute__((aligned(16))) bf16_t Vt[64 * 64];
    __shared__ __attribute__((aligned(16))) bf16_t Plds[128 * 64];   // ring
    __shared__ __attribute__((aligned(16))) bf16_t Prob[4 * 16 * 64];

    int tid = threadIdx.x;
    int wave = tid >> 6, lane = tid & 63, quad = lane >> 4, l16 = lane & 15;

    // decode: XCD k owns bh in [8k,8k+8); per-CU s_blk quadruple sums to 30.
    int linear = blockIdx.x;                 // 0..1023
    int xcd = linear & 7;
    int p = linear >> 3;                     // 0..127 within XCD
    int bh = xcd * 8 + ((p >> 2) & 7);
    int q4 = ((p >> 5) << 2) | (p & 3);      // 0..15
    int s_blk = (q4 < 8) ? q4 : 23 - q4;
    int nt = 17 + s_blk;
    int t0 = 0;
    int t1 = nt;

    int s0 = s_blk * 64;
    int b = bh >> 4, h = bh & 15;
    int srow0 = s0 + wave * 16;

    const bf16_t* qub = qu + ((size_t)(srow0 + l16) * B_ + b) * 1024 + h * 64 + quad * 8;
    const bf16_t* qvb = qv + ((size_t)(srow0 + l16) * B_ + b) * 1024 + h * 64 + quad * 8;
    bf16x8 aqu0 = *(const bf16x8*)(qub);
    bf16x8 aqu1 = *(const bf16x8*)(qub + 32);
    bf16x8 aqv0 = *(const bf16x8*)(qvb);
    bf16x8 aqv1 = *(const bf16x8*)(qvb + 32);

    f32x4 zero = {0.f, 0.f, 0.f, 0.f};
    f32x4 accO[4];
    #pragma unroll
    for (int ot = 0; ot < 4; ot++) accO[ot] = zero;
    float lrowp[4] = {0.f, 0.f, 0.f, 0.f};

    const int w0u = 960 - s0;
    const int woff = 48 - wave * 16;
    const float SCL = 0.125f * 1.44269504088896f;

    int jr = tid >> 3, seg8g = tid & 7;
    int jp = tid & 31, iseg = tid >> 5;
    uint* VtU = (uint*)&Vt[0];
    bf16_t* ProbW = Prob + (wave << 10);

    {
        int j0 = t0 * 64;
        const bf16_t* kp = kv + ((size_t)(j0 + jr) * B_ + b) * 2048 + h * 64 + seg8g * 8;
        uint4 ka = *(const uint4*)kp;
        uint4 kb = *(const uint4*)(kp + (size_t)32 * B_ * 2048);
        const bf16_t* vp = kv + ((size_t)(j0 + jp * 2) * B_ + b) * 2048 + 1024 + h * 64 + iseg * 8;
        u16x8 va = *(const u16x8*)vp;
        u16x8 vb = *(const u16x8*)(vp + (size_t)B_ * 2048);
        uint4 pd[4];
        #pragma unroll
        for (int r = 0; r < 4; r++) {
            int idx = tid + 256 * r;
            int pr = idx >> 3, pg = idx & 7;
            int lr = w0u + j0 + pr; if (lr > J_ - 1) lr = J_ - 1;
            pd[r] = *(const uint4*)(pm + (size_t)lr * 1024 + h * 64 + pg * 8);
        }
        *(uint4*)&Klds[SWZ(jr, seg8g * 8)] = ka;
        *(uint4*)&Klds[SWZ(jr + 32, seg8g * 8)] = kb;
        #pragma unroll
        for (int e = 0; e < 8; e++) {
            int row = iseg * 8 + e;
            VtU[(row << 5) + ((((jp >> 2) ^ (row & 7)) << 2)) + (jp & 3)] =
                (uint)va[e] | ((uint)vb[e] << 16);
        }
        #pragma unroll
        for (int r = 0; r < 4; r++) {
            int idx = tid + 256 * r;
            int pr = idx >> 3, pg = idx & 7;
            *(uint4*)&Plds[SWZ((w0u + j0 + pr) & 127, pg * 8)] = pd[r];
        }
    }
    __syncthreads();

    for (int it = t0; it < t1; it++) {
        int j0 = it * 64;
        bool pf = (it + 1 < t1);
        uint4 ka, kb, pd0, pd1;
        u16x8 va, vb;
        int pr0 = tid >> 3, pg0 = tid & 7;
        int pr1 = (tid + 256) >> 3, pg1 = tid & 7;
        if (pf) {
            int j1 = j0 + 64;
            const bf16_t* kp = kv + ((size_t)(j1 + jr) * B_ + b) * 2048 + h * 64 + seg8g * 8;
            ka = *(const uint4*)kp;
            kb = *(const uint4*)(kp + (size_t)32 * B_ * 2048);
            const bf16_t* vp = kv + ((size_t)(j1 + jp * 2) * B_ + b) * 2048 + 1024 + h * 64 + iseg * 8;
            va = *(const u16x8*)vp;
            vb = *(const u16x8*)(vp + (size_t)B_ * 2048);
            int lr0 = w0u + j0 + 128 + pr0; if (lr0 > J_ - 1) lr0 = J_ - 1;
            int lr1 = w0u + j0 + 128 + pr1; if (lr1 > J_ - 1) lr1 = J_ - 1;
            pd0 = *(const uint4*)(pm + (size_t)lr0 * 1024 + h * 64 + pg0 * 8);
            pd1 = *(const uint4*)(pm + (size_t)lr1 * 1024 + h * 64 + pg1 * 8);
        }

        f32x4 cs[4];
        #pragma unroll
        for (int t = 0; t < 4; t++) cs[t] = zero;
        __builtin_amdgcn_s_setprio(1);
        #pragma unroll
        for (int ks = 0; ks < 2; ks++) {
            bf16x8 aq = ks ? aqu1 : aqu0;
            #pragma unroll
            for (int t = 0; t < 4; t++) {
                bf16x8 bk = *(const bf16x8*)&Klds[SWZ(t * 16 + l16, ks * 32 + quad * 8)];
                cs[t] = MFMA16(aq, bk, cs[t]);
            }
        }
        f32x4 ep[5];
        #pragma unroll
        for (int t = 0; t < 5; t++) ep[t] = zero;
        #pragma unroll
        for (int ks = 0; ks < 2; ks++) {
            bf16x8 aq = ks ? aqv1 : aqv0;
            #pragma unroll
            for (int t = 0; t < 5; t++) {
                int prow = (w0u + j0 + woff + t * 16 + l16) & 127;
                bf16x8 bp = *(const bf16x8*)&Plds[SWZ(prow, ks * 32 + quad * 8)];
                ep[t] = MFMA16(aq, bp, ep[t]);
            }
        }
        __builtin_amdgcn_s_setprio(0);

        #pragma unroll
        for (int reg = 0; reg < 4; reg++) {
            int r = quad * 4 + reg;
            int s = srow0 + r;
            int idx = l16 + 15 - r;
            int srcl = quad * 16 + (idx & 15);
            float sh[5];
            #pragma unroll
            for (int t = 0; t < 5; t++) sh[t] = __shfl(ep[t][reg], srcl);
            float psum = 0.f;
            #pragma unroll
            for (int t = 0; t < 4; t++) {
                float pos = (idx < 16) ? sh[t] : sh[t + 1];
                float p2 = exp2f((cs[t][reg] + pos) * SCL);
                p2 = (j0 + t * 16 + l16 > P_ + s) ? 0.f : p2;
                ProbW[SWZ(r, t * 16 + l16)] = (bf16_t)p2;
                psum += p2;
            }
            lrowp[reg] += psum;
        }

        __builtin_amdgcn_s_setprio(1);
        #pragma unroll
        for (int ks = 0; ks < 2; ks++) {
            bf16x8 pa = *(const bf16x8*)&Prob[(wave << 10) + SWZ(l16, ks * 32 + quad * 8)];
            #pragma unroll
            for (int ot = 0; ot < 4; ot++) {
                bf16x8 bv = *(const bf16x8*)&Vt[SWZ(ot * 16 + l16, ks * 32 + quad * 8)];
                accO[ot] = MFMA16(pa, bv, accO[ot]);
            }
        }
        __builtin_amdgcn_s_setprio(0);

        __syncthreads();
        if (pf) {
            *(uint4*)&Klds[SWZ(jr, seg8g * 8)] = ka;
            *(uint4*)&Klds[SWZ(jr + 32, seg8g * 8)] = kb;
            #pragma unroll
            for (int e2 = 0; e2 < 8; e2++) {
                int row = iseg * 8 + e2;
                VtU[(row << 5) + ((((jp >> 2) ^ (row & 7)) << 2)) + (jp & 3)] =
                    (uint)va[e2] | ((uint)vb[e2] << 16);
            }
            *(uint4*)&Plds[SWZ((w0u + j0 + pr0) & 127, pg0 * 8)] = pd0;
            *(uint4*)&Plds[SWZ((w0u + j0 + pr1) & 127, pg1 * 8)] = pd1;
        }
        __syncthreads();
    }

    // fused normalize + direct bf16 store (row-sum is complete: block owns the row)
    #pragma unroll
    for (int reg = 0; reg < 4; reg++) {
        int r = quad * 4 + reg;
        int srow = srow0 + r;
        float l = lrowp[reg];
        #pragma unroll
        for (int d = 1; d < 16; d <<= 1) l += __shfl_xor(l, d);
        float inv = 1.0f / l;
        size_t rowoff = ((size_t)srow * B_ + b) * 1024 + h * 64;
        #pragma unroll
        for (int ot = 0; ot < 4; ot++)
            awv[rowoff + ot * 16 + l16] = (bf16_t)(accO[ot][reg] * inv);
    }
}

// ---------------- LayerNorm over E=1024 ----------------
__global__ __launch_bounds__(256) void ln_kernel(const float* __restrict__ x,
                                                 const float* __restrict__ gamma,
                                                 const float* __restrict__ beta,
                                                 float* __restrict__ out) {
    int row = blockIdx.x, tid = threadIdx.x;
    int lane = tid & 63, wave = tid >> 6;
    float4 v = ((const float4*)(x + (size_t)row * 1024))[tid];
    float s = v.x + v.y + v.z + v.w;
    float ss = v.x * v.x + v.y * v.y + v.z * v.z + v.w * v.w;
    #pragma unroll
    for (int sh = 1; sh < 64; sh <<= 1) { s += __shfl_xor(s, sh); ss += __shfl_xor(ss, sh); }
    __shared__ float red[8];
    if (lane == 0) { red[wave] = s; red[4 + wave] = ss; }
    __syncthreads();
    s = red[0] + red[1] + red[2] + red[3];
    ss = red[4] + red[5] + red[6] + red[7];
    float mean = s * (1.f / 1024.f);
    float var = ss * (1.f / 1024.f) - mean * mean;
    float inv = rsqrtf(var + 1e-5f);
    float4 g = ((const float4*)gamma)[tid];
    float4 bt = ((const float4*)beta)[tid];
    float4 o;
    o.x = (v.x - mean) * inv * g.x + bt.x;
    o.y = (v.y - mean) * inv * g.y + bt.y;
    o.z = (v.z - mean) * inv * g.z + bt.z;
    o.w = (v.w - mean) * inv * g.w + bt.w;
    ((float4*)(out + (size_t)row * 1024))[tid] = o;
}

extern "C" void kernel_launch(void* const* d_in, const int* in_sizes, int n_in,
                              void* d_out, int out_size, void* d_ws, size_t ws_size,
                              hipStream_t stream) {
    const float* inputMHA = (const float*)d_in[0];
    const float* posEmb   = (const float*)d_in[1];
    const float* memory   = (const float*)d_in[2];
    const float* u        = (const float*)d_in[3];
    const float* v        = (const float*)d_in[4];
    const float* W_kv     = (const float*)d_in[6];
    const float* W_q      = (const float*)d_in[7];
    const float* W_p      = (const float*)d_in[8];
    const float* W_o      = (const float*)d_in[9];
    const float* gamma    = (const float*)d_in[10];
    const float* beta     = (const float*)d_in[11];
    float* out = (float*)d_out;

    char* ws = (char*)d_ws;
    size_t off = 0;
    auto alloc = [&](size_t bytes) -> void* {
        void* p = ws + off;
        off += (bytes + 255) & ~(size_t)255;
        return p;
    };
    bf16_t* Xbf  = (bf16_t*)alloc((size_t)J_ * B_ * E_ * 2);
    bf16_t* Wkvt = (bf16_t*)alloc((size_t)2048 * 1024 * 2);
    bf16_t* Wqt  = (bf16_t*)alloc((size_t)1024 * 1024 * 2);
    bf16_t* Wpt  = (bf16_t*)alloc((size_t)1024 * 1024 * 2);
    bf16_t* Wot  = (bf16_t*)alloc((size_t)1024 * 1024 * 2);
    bf16_t* Pemb = (bf16_t*)alloc((size_t)2048 * 1024 * 2);
    bf16_t* kvb  = (bf16_t*)alloc((size_t)8192 * 2048 * 2);
    bf16_t* qub  = (bf16_t*)alloc((size_t)4096 * 1024 * 2);
    bf16_t* qvb  = (bf16_t*)alloc((size_t)4096 * 1024 * 2);
    bf16_t* pb   = (bf16_t*)alloc((size_t)2048 * 1024 * 2);
    bf16_t* awvb = (bf16_t*)alloc((size_t)4096 * 1024 * 2);
    float*  opre = (float*)alloc((size_t)4096 * 1024 * 4);

    cvt_all_kernel<<<10240, 256, 0, stream>>>(memory, inputMHA, posEmb, Xbf, Pemb);
    trans_all_kernel<<<dim3(64, 32, 4), dim3(32, 8), 0, stream>>>(
        W_kv, Wkvt, W_q, Wqt, W_p, Wpt, W_o, Wot);

    gemm3_kernel<<<1408, 256, 0, stream>>>(Xbf, Wkvt, kvb, Wqt, qub, qvb, u, v, Pemb, Wpt, pb);

    flash_kernel<<<1024, 256, 0, stream>>>(qub, qvb, kvb, pb, awvb);

    gemmo_kernel<<<256, 256, 0, stream>>>(awvb, Wot, inputMHA, opre);
    ln_kernel<<<S_ * B_, 256, 0, stream>>>(opre, gamma, beta, out);
}